// Round 12
// baseline (2072.907 us; speedup 1.0000x reference)
//
#include <hip/hip_runtime.h>
#include <cstddef>
#include <cstdint>

#define NTOTC 16384
#define HC 256
#define LC 6
#define NEDGEC 262144
#define NHEADSC 8

typedef __attribute__((ext_vector_type(8))) short short8;
typedef __attribute__((ext_vector_type(4))) float f32x4;

__device__ __forceinline__ unsigned short f2bf(float f) {
    unsigned int u = __float_as_uint(f);
    u += 0x7fff + ((u >> 16) & 1);   // round-to-nearest-even
    return (unsigned short)(u >> 16);
}
__device__ __forceinline__ float bf2f(unsigned short s) {
    return __uint_as_float(((unsigned int)s) << 16);
}
// packed f32x2 -> bf16x2 (RTNE, identical rounding to f2bf); 1 instr for 2 elems
__device__ __forceinline__ unsigned int cvt_pk_bf16(float lo, float hi) {
    unsigned int r;
    asm("v_cvt_pk_bf16_f32 %0, %1, %2" : "=v"(r) : "v"(lo), "v"(hi));
    return r;
}
__device__ __forceinline__ void async_copy16(const void* g, void* l) {
    __builtin_amdgcn_global_load_lds(
        (const __attribute__((address_space(1))) unsigned int*)g,
        (__attribute__((address_space(3))) unsigned int*)l, 16, 0, 0);
}
// fast transcendentals; ~1e-6 rel err, negligible vs bf16
__device__ __forceinline__ float exp_f(float v) {
    return __builtin_amdgcn_exp2f(v * 1.4426950408889634f);
}
__device__ __forceinline__ float silu_f(float v) {
    return v * __builtin_amdgcn_rcpf(1.0f + __builtin_amdgcn_exp2f(-v * 1.4426950408889634f));
}
__device__ __forceinline__ float tanh_f(float v) {
    float e = __builtin_amdgcn_exp2f(v * 2.8853900817779268f);   // e^(2v)
    return 1.0f - 2.0f * __builtin_amdgcn_rcpf(1.0f + e);
}

// ---- DPP 16-lane reductions (VALU, no LDS pipe; tree identical to shfl_xor 1,2,4,8) ----
template<int CTRL>
__device__ __forceinline__ float dpp_movf(float x) {
    return __int_as_float(__builtin_amdgcn_update_dpp(
        0, __float_as_int(x), CTRL, 0xF, 0xF, true));
}
__device__ __forceinline__ float sum16(float x) {
    x += dpp_movf<0xB1>(x);    // quad_perm [1,0,3,2]  (xor 1)
    x += dpp_movf<0x4E>(x);    // quad_perm [2,3,0,1]  (xor 2)
    x += dpp_movf<0x141>(x);   // row_half_mirror      (xor 4 equiv.)
    x += dpp_movf<0x140>(x);   // row_mirror           (xor 8 equiv.)
    return x;
}
__device__ __forceinline__ float max16(float x) {
    x = fmaxf(x, dpp_movf<0xB1>(x));
    x = fmaxf(x, dpp_movf<0x4E>(x));
    x = fmaxf(x, dpp_movf<0x141>(x));
    x = fmaxf(x, dpp_movf<0x140>(x));
    return x;
}

// ================= weight conversion =================
__global__ __launch_bounds__(256) void conv_bf16_kernel(
    const float* __restrict__ in, unsigned short* __restrict__ out, int n)
{
    int n4 = n >> 2;   // all call sites have n % 4 == 0
    for (int i = blockIdx.x * 256 + threadIdx.x; i < n4; i += gridDim.x * 256) {
        float4 v = ((const float4*)in)[i];
        ((uint2*)out)[i] = make_uint2(cvt_pk_bf16(v.x, v.y), cvt_pk_bf16(v.z, v.w));
    }
}

// phi_e_w1 [L,256,513] -> stacked bf16 [L,512,256] ([W1a;W1b]) + fp32 dist column [L,256]
__global__ __launch_bounds__(256) void conv_pe1_kernel(
    const float* __restrict__ in, unsigned short* __restrict__ outk, float* __restrict__ wlast)
{
    int idx = blockIdx.x * 256 + threadIdx.x;
    if (idx >= LC * 256 * 513) return;
    int l = idx / (256 * 513);
    int rem = idx % (256 * 513);
    int n = rem / 513;
    int k = rem % 513;
    float v = in[idx];
    if (k == 512) wlast[l * 256 + n] = v;
    else if (k < 256) outk[(size_t)l * 512 * 256 + (size_t)n * 256 + k] = f2bf(v);
    else outk[(size_t)l * 512 * 256 + (size_t)(256 + n) * 256 + (k - 256)] = f2bf(v);
}

// ================= counting sort of edges by col =================
__global__ __launch_bounds__(256) void hist_kernel(
    const int* __restrict__ col, int* __restrict__ cnt)
{
    int e = blockIdx.x * 256 + threadIdx.x;
    atomicAdd(&cnt[col[e]], 1);
}

__global__ __launch_bounds__(256) void scan16k_kernel(
    const int* __restrict__ cnt, int* __restrict__ ptrw)
{
    __shared__ int partial[256];
    const int t = threadIdx.x;
    const int base = t * 64;
    int loc[64];
    int s = 0;
#pragma unroll
    for (int i = 0; i < 64; i++) { loc[i] = s; s += cnt[base + i]; }
    partial[t] = s;
    __syncthreads();
    if (t == 0) {
        int run = 0;
        for (int i = 0; i < 256; i++) { int tmp = partial[i]; partial[i] = run; run += tmp; }
    }
    __syncthreads();
    int off = partial[t];
#pragma unroll
    for (int i = 0; i < 64; i++) ptrw[base + i] = off + loc[i];
}

__global__ __launch_bounds__(256) void permute_kernel(
    const int* __restrict__ row, const int* __restrict__ col, int* __restrict__ ptrw,
    int* __restrict__ rowP, int* __restrict__ colP)
{
    int e = blockIdx.x * 256 + threadIdx.x;
    int c = col[e];
    int pos = atomicAdd(&ptrw[c], 1);
    rowP[pos] = row[e];
    colP[pos] = c;
}

// ================= generic MFMA GEMM: C = act(A @ W^T + bias)(+R) =================
// MT = M-tile (128 or 64). Block tile = MT x 128, 4 waves.
template<int MT, int ACT, bool RES, bool WF, bool WB>
__global__ __launch_bounds__(256) void mgemm_kernel(
    const unsigned short* __restrict__ A, const unsigned short* __restrict__ W,
    const float* __restrict__ bias, const float* __restrict__ R,
    float* __restrict__ Cf, unsigned short* __restrict__ Cb,
    int M, int N, int K)
{
    constexpr int FI = MT / 32;            // M-fragments per wave (4 or 2)
    __shared__ unsigned short As[MT * 32];
    __shared__ unsigned short Bs[128 * 32];
    const int tid = threadIdx.x;
    const int lane = tid & 63, wave = tid >> 6;
    const int quad = lane >> 4, l16 = lane & 15;
    const int wm = (wave >> 1) * (MT / 2), wn = (wave & 1) * 64;
    const int m0 = blockIdx.x * MT, n0 = blockIdx.y * 128;
    f32x4 acc[FI][4] = {};
    const int rbase = (lane >> 2);
    const int kk = (lane & 3) * 8;

    for (int k0 = 0; k0 < K; k0 += 32) {
#pragma unroll
        for (int c = 0; c < MT / 64; c++) {
            int t = wave * (MT / 64) + c;
            int r = t * 16 + rbase;
            async_copy16(A + (size_t)(m0 + r) * K + k0 + kk, &As[t * 512 + lane * 8]);
        }
#pragma unroll
        for (int c = 0; c < 2; c++) {
            int t = wave * 2 + c;
            int r = t * 16 + rbase;
            async_copy16(W + (size_t)(n0 + r) * K + k0 + kk, &Bs[t * 512 + lane * 8]);
        }
        __syncthreads();
        short8 af[FI], bfr[4];
#pragma unroll
        for (int i = 0; i < FI; i++)
            af[i] = *(const short8*)&As[(wm + i * 16 + l16) * 32 + quad * 8];
#pragma unroll
        for (int j = 0; j < 4; j++)
            bfr[j] = *(const short8*)&Bs[(wn + j * 16 + l16) * 32 + quad * 8];
#pragma unroll
        for (int i = 0; i < FI; i++)
#pragma unroll
            for (int j = 0; j < 4; j++)
                acc[i][j] = __builtin_amdgcn_mfma_f32_16x16x32_bf16(af[i], bfr[j], acc[i][j], 0, 0, 0);
        __syncthreads();
    }
#pragma unroll
    for (int jp = 0; jp < 2; jp++) {
        int col0 = n0 + wn + jp * 32 + l16;
        int col1 = col0 + 16;
        float bi0 = bias[col0], bi1 = bias[col1];
#pragma unroll
        for (int i = 0; i < FI; i++) {
#pragma unroll
            for (int rg = 0; rg < 4; rg++) {
                int row = m0 + wm + i * 16 + quad * 4 + rg;
                float v0 = acc[i][jp * 2][rg] + bi0;
                float v1 = acc[i][jp * 2 + 1][rg] + bi1;
                if (ACT == 1) { v0 = silu_f(v0); v1 = silu_f(v1); }
                if (ACT == 2) {
                    v0 = 0.5f * v0 * (1.0f + erff(v0 * 0.7071067811865476f));
                    v1 = 0.5f * v1 * (1.0f + erff(v1 * 0.7071067811865476f));
                }
                if (RES) {
                    v0 += R[(size_t)row * N + col0];
                    v1 += R[(size_t)row * N + col1];
                }
                if (WF) {
                    Cf[(size_t)row * N + col0] = v0;
                    Cf[(size_t)row * N + col1] = v1;
                }
                if (WB) {
                    unsigned int pk = cvt_pk_bf16(v0, v1);
                    Cb[(size_t)row * N + col0] = (unsigned short)pk;
                    Cb[(size_t)row * N + col1] = (unsigned short)(pk >> 16);
                }
            }
        }
    }
}

// ================= FUSED edge pipeline (M=64, rel/dist inline) =================
// blockIdx is XCD-swizzled (bijective, 4096 % 8 == 0): each XCD gets a contiguous
// 512-block chunk of the col-sorted edge range -> xcat row/col gathers and hmsg
// boundary atomics stay in one XCD's L2.
__global__ __launch_bounds__(256, 4) void fused_edge_kernel(
    const unsigned short* __restrict__ xcat, const float* __restrict__ cur,
    const int* __restrict__ rowP, const int* __restrict__ colP,
    const float* __restrict__ wlast, const float* __restrict__ b1,
    const unsigned short* __restrict__ W2, const float* __restrict__ b2,
    const float* __restrict__ lg, const float* __restrict__ lb,
    const unsigned short* __restrict__ W3, const float* __restrict__ b3,
    const float* __restrict__ w2v, const float* __restrict__ b2s,
    float* __restrict__ hmsg, float* __restrict__ posupd)
{
    __shared__ __align__(16) unsigned short tS[64 * 264];
    __shared__ float redS[4][64];
    __shared__ float redS2[4][64];
    __shared__ int rowS[64], colS[64], flagS[64];
    __shared__ float distS[64];
    __shared__ float relS[64][3];
    __shared__ float cfS[64];
    __shared__ int openS[2];   // [0]: first col continues from prev block; [1]: last col continues into next

    const int tid = threadIdx.x;
    const int lane = tid & 63, wave = tid >> 6;
    const int quad = lane >> 4, l16 = lane & 15;
    const int wn = wave * 64;
    // XCD-aware bijective swizzle: nwg = 4096, 8 XCDs, 512 blocks/XCD chunk
    const int swz = (blockIdx.x & 7) * (NEDGEC / 64 / 8) + (blockIdx.x >> 3);
    const int m0 = swz * 64;

    if (tid < 64) {
        int r = rowP[m0 + tid];
        int c = colP[m0 + tid];
        rowS[tid] = r;
        colS[tid] = c;
        float rx = cur[(size_t)r * 3 + 0] - cur[(size_t)c * 3 + 0];
        float ry = cur[(size_t)r * 3 + 1] - cur[(size_t)c * 3 + 1];
        float rz = cur[(size_t)r * 3 + 2] - cur[(size_t)c * 3 + 2];
        relS[tid][0] = rx;
        relS[tid][1] = ry;
        relS[tid][2] = rz;
        float dx = rx + 1e-8f, dy = ry + 1e-8f, dz = rz + 1e-8f;  // ref adds eps per component
        distS[tid] = sqrtf(dx * dx + dy * dy + dz * dz);
    }
    if (tid == 64) {
        openS[0] = (m0 > 0) && (colP[m0 - 1] == colP[m0]);
        openS[1] = (m0 + 64 < NEDGEC) && (colP[m0 + 64] == colP[m0 + 63]);
    }
    __syncthreads();
    if (tid < 64) flagS[tid] = (tid == 63) || (colS[tid] != colS[tid + 1]);

    // ---- Stage 1: gather-add replacing edge GEMM1 (16B vectorized) ----
    {
        const int half = lane >> 5;          // 0/1: which of the wave's 2 rows
        const int cb = (lane & 31) * 8;      // 8 adjacent cols per lane (16B)
        float4 wlA = *(const float4*)&wlast[cb];
        float4 wlB = *(const float4*)&wlast[cb + 4];
        float4 b1A = *(const float4*)&b1[cb];
        float4 b1B = *(const float4*)&b1[cb + 4];
#pragma unroll
        for (int rr = 0; rr < 8; rr++) {
            int r = rr * 8 + wave * 2 + half;
            const short8 ua = *(const short8*)(xcat + (size_t)rowS[r] * 512 + cb);
            const short8 ub = *(const short8*)(xcat + (size_t)colS[r] * 512 + 256 + cb);
            float dv = distS[r];
            float v0 = bf2f((unsigned short)ua[0]) + bf2f((unsigned short)ub[0]) + dv * wlA.x + b1A.x;
            float v1 = bf2f((unsigned short)ua[1]) + bf2f((unsigned short)ub[1]) + dv * wlA.y + b1A.y;
            float v2 = bf2f((unsigned short)ua[2]) + bf2f((unsigned short)ub[2]) + dv * wlA.z + b1A.z;
            float v3 = bf2f((unsigned short)ua[3]) + bf2f((unsigned short)ub[3]) + dv * wlA.w + b1A.w;
            float v4 = bf2f((unsigned short)ua[4]) + bf2f((unsigned short)ub[4]) + dv * wlB.x + b1B.x;
            float v5 = bf2f((unsigned short)ua[5]) + bf2f((unsigned short)ub[5]) + dv * wlB.y + b1B.y;
            float v6 = bf2f((unsigned short)ua[6]) + bf2f((unsigned short)ub[6]) + dv * wlB.z + b1B.z;
            float v7 = bf2f((unsigned short)ua[7]) + bf2f((unsigned short)ub[7]) + dv * wlB.w + b1B.w;
            uint4 o;
            o.x = cvt_pk_bf16(silu_f(v0), silu_f(v1));
            o.y = cvt_pk_bf16(silu_f(v2), silu_f(v3));
            o.z = cvt_pk_bf16(silu_f(v4), silu_f(v5));
            o.w = cvt_pk_bf16(silu_f(v6), silu_f(v7));
            *(uint4*)&tS[r * 264 + cb] = o;
        }
    }
    __syncthreads();

    f32x4 acc[4][4];

    // ---- GEMM2: K=256, A from tS, W2 direct; NO barriers in k-loop ----
#pragma unroll
    for (int i = 0; i < 4; i++)
#pragma unroll
        for (int j = 0; j < 4; j++) acc[i][j] = (f32x4){0.f, 0.f, 0.f, 0.f};
#pragma unroll
    for (int k0 = 0; k0 < 256; k0 += 32) {
        short8 af[4], bfr[4];
#pragma unroll
        for (int j = 0; j < 4; j++)
            bfr[j] = *(const short8*)(W2 + (size_t)(wn + j * 16 + l16) * 256 + k0 + quad * 8);
#pragma unroll
        for (int i = 0; i < 4; i++)
            af[i] = *(const short8*)&tS[(i * 16 + l16) * 264 + k0 + quad * 8];
#pragma unroll
        for (int i = 0; i < 4; i++)
#pragma unroll
            for (int j = 0; j < 4; j++)
                acc[i][j] = __builtin_amdgcn_mfma_f32_16x16x32_bf16(af[i], bfr[j], acc[i][j], 0, 0, 0);
    }
    __syncthreads();
    // epilogue 2: LN -> m -> tS (overwrite)
    {
        float b2j[4], gj[4], bbj[4];
#pragma unroll
        for (int j = 0; j < 4; j++) {
            int col = wn + j * 16 + l16;
            b2j[j] = b2[col];
            gj[j] = lg[col];
            bbj[j] = lb[col];
        }
        // fold bias into acc once (used by both reduce and write passes)
#pragma unroll
        for (int i = 0; i < 4; i++)
#pragma unroll
            for (int j = 0; j < 4; j++)
#pragma unroll
                for (int rg = 0; rg < 4; rg++) acc[i][j][rg] += b2j[j];
#pragma unroll
        for (int i = 0; i < 4; i++)
#pragma unroll
            for (int rg = 0; rg < 4; rg++) {
                float p = 0.0f, q = 0.0f;
#pragma unroll
                for (int j = 0; j < 4; j++) {
                    float v = acc[i][j][rg];
                    p += v; q += v * v;
                }
                p = sum16(p);
                q = sum16(q);
                if (l16 == 0) {
                    int row = i * 16 + quad * 4 + rg;
                    redS[wave][row] = p;
                    redS2[wave][row] = q;
                }
            }
        __syncthreads();
#pragma unroll
        for (int i = 0; i < 4; i++)
#pragma unroll
            for (int rg = 0; rg < 4; rg++) {
                int row = i * 16 + quad * 4 + rg;
                float s = redS[0][row] + redS[1][row] + redS[2][row] + redS[3][row];
                float qq = redS2[0][row] + redS2[1][row] + redS2[2][row] + redS2[3][row];
                float mean = s * (1.0f / 256.0f);
                float rstd = 1.0f / sqrtf(qq * (1.0f / 256.0f) - mean * mean + 1e-5f);
                float y0 = (acc[i][0][rg] - mean) * rstd * gj[0] + bbj[0];
                float y1 = (acc[i][1][rg] - mean) * rstd * gj[1] + bbj[1];
                float y2 = (acc[i][2][rg] - mean) * rstd * gj[2] + bbj[2];
                float y3 = (acc[i][3][rg] - mean) * rstd * gj[3] + bbj[3];
                unsigned int pA = cvt_pk_bf16(y0, y1);
                unsigned int pB = cvt_pk_bf16(y2, y3);
                unsigned short* tb = &tS[row * 264 + wn + l16];
                tb[0]  = (unsigned short)pA;
                tb[16] = (unsigned short)(pA >> 16);
                tb[32] = (unsigned short)pB;
                tb[48] = (unsigned short)(pB >> 16);
            }
    }
    __syncthreads();

    // ---- segmented scatter of m into hmsg: wave w owns cols [64w,64w+64), 1 col/lane ----
    // Flush ONLY at true segment boundaries. Interior segments (wholly contained in this
    // block) are exclusively owned -> plain store (hmsg pre-zeroed). Only the first
    // segment (if continued from prev block) and last (if continued into next) need atomics.
    {
        const int c = wn + lane;             // one column per lane
        const bool openL = openS[0] != 0;
        const bool openR = openS[1] != 0;
        float s = 0.0f;
        bool first = true;
        for (int r = 0; r < 64; r++) {
            s += bf2f(tS[r * 264 + c]);
            if (flagS[r]) {
                float* dst = &hmsg[(size_t)colS[r] * 256 + c];
                bool needAtomic = (first && openL) || (r == 63 && openR);
                if (needAtomic) atomicAdd(dst, s);
                else *dst = s;
                s = 0.0f;
                first = false;
            }
        }
    }

    // ---- GEMM3: K=256, A = m from tS, W3 direct ----
#pragma unroll
    for (int i = 0; i < 4; i++)
#pragma unroll
        for (int j = 0; j < 4; j++) acc[i][j] = (f32x4){0.f, 0.f, 0.f, 0.f};
#pragma unroll
    for (int k0 = 0; k0 < 256; k0 += 32) {
        short8 af[4], bfr[4];
#pragma unroll
        for (int j = 0; j < 4; j++)
            bfr[j] = *(const short8*)(W3 + (size_t)(wn + j * 16 + l16) * 256 + k0 + quad * 8);
#pragma unroll
        for (int i = 0; i < 4; i++)
            af[i] = *(const short8*)&tS[(i * 16 + l16) * 264 + k0 + quad * 8];
#pragma unroll
        for (int i = 0; i < 4; i++)
#pragma unroll
            for (int j = 0; j < 4; j++)
                acc[i][j] = __builtin_amdgcn_mfma_f32_16x16x32_bf16(af[i], bfr[j], acc[i][j], 0, 0, 0);
    }
    // epilogue 3
    {
        float b3j[4], w2j[4];
#pragma unroll
        for (int j = 0; j < 4; j++) {
            int col = wn + j * 16 + l16;
            b3j[j] = b3[col];
            w2j[j] = w2v[col];
        }
#pragma unroll
        for (int i = 0; i < 4; i++)
#pragma unroll
            for (int rg = 0; rg < 4; rg++) {
                float p = 0.0f;
#pragma unroll
                for (int j = 0; j < 4; j++)
                    p += silu_f(acc[i][j][rg] + b3j[j]) * w2j[j];
                p = sum16(p);
                if (l16 == 0) redS[wave][i * 16 + quad * 4 + rg] = p;
            }
        __syncthreads();
        if (tid < 64) {
            float tot = redS[0][tid] + redS[1][tid] + redS[2][tid] + redS[3][tid] + b2s[0];
            cfS[tid] = tanh_f(tot);
        }
        __syncthreads();
        // pos scatter: 12 lanes = 3 components x 4 row-groups (chain 64 -> 16)
        if (tid < 12) {
            const int comp = tid % 3;
            const int gbase = (tid / 3) * 16;
            float s = 0.0f;
#pragma unroll
            for (int rr = 0; rr < 16; rr++) {
                int r = gbase + rr;
                s += relS[r][comp] * cfS[r];
                if (flagS[r] || rr == 15) {
                    atomicAdd(&posupd[(size_t)colS[r] * 3 + comp], s);
                    s = 0.0f;
                }
            }
        }
    }
}

// ============ phi_h fused + cur-update + hmsg re-zero (M=32, direct-B) ============
// h = LN2(h + LN1(silu((h+hmsg)@W1^T+b1)@W2^T+b2)); cur += ps[l]*posupd (posupd zeroed);
// block zeroes its own hmsg rows for the next layer. Grid = NTOT/32.
__global__ __launch_bounds__(256) void phi_h_fused_kernel(
    const float* __restrict__ h_in, float* __restrict__ hmsg,
    const unsigned short* __restrict__ W1, const float* __restrict__ b1v,
    const unsigned short* __restrict__ W2, const float* __restrict__ bias,
    const float* __restrict__ g1, const float* __restrict__ bb1,
    const float* __restrict__ g2, const float* __restrict__ bb2,
    float* __restrict__ h, unsigned short* __restrict__ h_bf,
    float* __restrict__ cur, float* __restrict__ posupd, const float* __restrict__ psv, int l)
{
    __shared__ __align__(16) unsigned short As[32 * 32];
    __shared__ __align__(16) unsigned short tS[32 * 264];
    __shared__ float redS[4][32];
    __shared__ float redS2[4][32];
    const int tid = threadIdx.x;
    const int lane = tid & 63, wave = tid >> 6;
    const int quad = lane >> 4, l16 = lane & 15;
    const int wn = wave * 64;
    const int m0 = blockIdx.x * 32;
    f32x4 acc[2][4] = {};

    // side job: cur += ps[l] * posupd; posupd = 0  (49152 elements over first 192 blocks)
    {
        int e = blockIdx.x * 256 + tid;
        if (e < NTOTC * 3) {
            cur[e] += psv[l] * posupd[e];
            posupd[e] = 0.0f;
        }
    }

    // GEMM1: A = bf16(h+hmsg) staged per k-step; B = W1 direct from L2
    for (int k0 = 0; k0 < 256; k0 += 32) {
        {
            int r = tid >> 3, kg = (tid & 7) * 4;
            float4 a = *(const float4*)&h_in[(size_t)(m0 + r) * 256 + k0 + kg];
            float4 b = *(const float4*)&hmsg[(size_t)(m0 + r) * 256 + k0 + kg];
            unsigned int p0 = cvt_pk_bf16(a.x + b.x, a.y + b.y);
            unsigned int p1 = cvt_pk_bf16(a.z + b.z, a.w + b.w);
            *(uint2*)&As[r * 32 + kg] = make_uint2(p0, p1);
        }
        __syncthreads();
        short8 bfr[4];
#pragma unroll
        for (int j = 0; j < 4; j++)
            bfr[j] = *(const short8*)(W1 + (size_t)(wn + j * 16 + l16) * 256 + k0 + quad * 8);
#pragma unroll
        for (int i = 0; i < 2; i++) {
            short8 af = *(const short8*)&As[(i * 16 + l16) * 32 + quad * 8];
#pragma unroll
            for (int j = 0; j < 4; j++)
                acc[i][j] = __builtin_amdgcn_mfma_f32_16x16x32_bf16(af, bfr[j], acc[i][j], 0, 0, 0);
        }
        __syncthreads();
    }
    // zero this block's hmsg rows (fully consumed above) for the next layer
    {
        size_t base = (size_t)m0 * 256;
        float4 z = {0.f, 0.f, 0.f, 0.f};
#pragma unroll
        for (int t = 0; t < 8; t++)
            *(float4*)&hmsg[base + (size_t)(t * 256 + tid) * 4] = z;
    }
    {
        float b1j[4];
#pragma unroll
        for (int j = 0; j < 4; j++) b1j[j] = b1v[wn + j * 16 + l16];
#pragma unroll
        for (int i = 0; i < 2; i++)
#pragma unroll
            for (int rg = 0; rg < 4; rg++) {
                int row = i * 16 + quad * 4 + rg;
                float s0 = silu_f(acc[i][0][rg] + b1j[0]);
                float s1 = silu_f(acc[i][1][rg] + b1j[1]);
                float s2 = silu_f(acc[i][2][rg] + b1j[2]);
                float s3 = silu_f(acc[i][3][rg] + b1j[3]);
                unsigned int pA = cvt_pk_bf16(s0, s1);
                unsigned int pB = cvt_pk_bf16(s2, s3);
                unsigned short* tb = &tS[row * 264 + wn + l16];
                tb[0]  = (unsigned short)pA;
                tb[16] = (unsigned short)(pA >> 16);
                tb[32] = (unsigned short)pB;
                tb[48] = (unsigned short)(pB >> 16);
            }
    }
    __syncthreads();

    // GEMM2: A = tS, B = W2 direct; no barriers in k-loop
#pragma unroll
    for (int i = 0; i < 2; i++)
#pragma unroll
        for (int j = 0; j < 4; j++) acc[i][j] = (f32x4){0.f, 0.f, 0.f, 0.f};
#pragma unroll
    for (int k0 = 0; k0 < 256; k0 += 32) {
        short8 af[2], bfr[4];
#pragma unroll
        for (int j = 0; j < 4; j++)
            bfr[j] = *(const short8*)(W2 + (size_t)(wn + j * 16 + l16) * 256 + k0 + quad * 8);
#pragma unroll
        for (int i = 0; i < 2; i++)
            af[i] = *(const short8*)&tS[(i * 16 + l16) * 264 + k0 + quad * 8];
#pragma unroll
        for (int i = 0; i < 2; i++)
#pragma unroll
            for (int j = 0; j < 4; j++)
                acc[i][j] = __builtin_amdgcn_mfma_f32_16x16x32_bf16(af[i], bfr[j], acc[i][j], 0, 0, 0);
    }

    float bj[4], g1j[4], b1j[4], g2j[4], b2j[4];
#pragma unroll
    for (int j = 0; j < 4; j++) {
        int col = wn + j * 16 + l16;
        bj[j] = bias[col];
        g1j[j] = g1[col]; b1j[j] = bb1[col];
        g2j[j] = g2[col]; b2j[j] = bb2[col];
    }
    // fold bias once
#pragma unroll
    for (int i = 0; i < 2; i++)
#pragma unroll
        for (int j = 0; j < 4; j++)
#pragma unroll
            for (int rg = 0; rg < 4; rg++) acc[i][j][rg] += bj[j];
#pragma unroll
    for (int i = 0; i < 2; i++)
#pragma unroll
        for (int rg = 0; rg < 4; rg++) {
            float p = 0.0f, q = 0.0f;
#pragma unroll
            for (int j = 0; j < 4; j++) {
                float v = acc[i][j][rg];
                p += v; q += v * v;
            }
            p = sum16(p);
            q = sum16(q);
            if (l16 == 0) {
                int rl = i * 16 + quad * 4 + rg;
                redS[wave][rl] = p;
                redS2[wave][rl] = q;
            }
        }
    __syncthreads();
#pragma unroll
    for (int i = 0; i < 2; i++)
#pragma unroll
        for (int rg = 0; rg < 4; rg++) {
            int rl = i * 16 + quad * 4 + rg;
            float s = redS[0][rl] + redS[1][rl] + redS[2][rl] + redS[3][rl];
            float qq = redS2[0][rl] + redS2[1][rl] + redS2[2][rl] + redS2[3][rl];
            float mean = s * (1.0f / 256.0f);
            float rstd = 1.0f / sqrtf(qq * (1.0f / 256.0f) - mean * mean + 1e-5f);
#pragma unroll
            for (int j = 0; j < 4; j++) {
                int col = wn + j * 16 + l16;
                float hu = (acc[i][j][rg] - mean) * rstd * g1j[j] + b1j[j];
                acc[i][j][rg] = hu + h_in[(size_t)(m0 + rl) * 256 + col];
            }
        }
    __syncthreads();
#pragma unroll
    for (int i = 0; i < 2; i++)
#pragma unroll
        for (int rg = 0; rg < 4; rg++) {
            float p = 0.0f, q = 0.0f;
#pragma unroll
            for (int j = 0; j < 4; j++) {
                float v = acc[i][j][rg];
                p += v; q += v * v;
            }
            p = sum16(p);
            q = sum16(q);
            if (l16 == 0) {
                int rl = i * 16 + quad * 4 + rg;
                redS[wave][rl] = p;
                redS2[wave][rl] = q;
            }
        }
    __syncthreads();
#pragma unroll
    for (int i = 0; i < 2; i++)
#pragma unroll
        for (int rg = 0; rg < 4; rg++) {
            int rl = i * 16 + quad * 4 + rg;
            float s = redS[0][rl] + redS[1][rl] + redS[2][rl] + redS[3][rl];
            float qq = redS2[0][rl] + redS2[1][rl] + redS2[2][rl] + redS2[3][rl];
            float mean = s * (1.0f / 256.0f);
            float rstd = 1.0f / sqrtf(qq * (1.0f / 256.0f) - mean * mean + 1e-5f);
            size_t orow = (size_t)(m0 + rl) * 256;
            float y0 = (acc[i][0][rg] - mean) * rstd * g2j[0] + b2j[0];
            float y1 = (acc[i][1][rg] - mean) * rstd * g2j[1] + b2j[1];
            float y2 = (acc[i][2][rg] - mean) * rstd * g2j[2] + b2j[2];
            float y3 = (acc[i][3][rg] - mean) * rstd * g2j[3] + b2j[3];
            h[orow + wn + l16]      = y0;
            h[orow + wn + 16 + l16] = y1;
            h[orow + wn + 32 + l16] = y2;
            h[orow + wn + 48 + l16] = y3;
            unsigned int pA = cvt_pk_bf16(y0, y1);
            unsigned int pB = cvt_pk_bf16(y2, y3);
            unsigned short* hb = h_bf + orow + wn + l16;
            hb[0]  = (unsigned short)pA;
            hb[16] = (unsigned short)(pA >> 16);
            hb[32] = (unsigned short)pB;
            hb[48] = (unsigned short)(pB >> 16);
        }
}

// ============ fused node GEMM + LN epilogue (attn-out path; M=32, direct-B) ============
// Grid = NTOT/32.
__global__ __launch_bounds__(256) void node_fused_kernel(
    const unsigned short* __restrict__ A, const unsigned short* __restrict__ W,
    const float* __restrict__ bias,
    const float* __restrict__ g1, const float* __restrict__ b1,
    float* __restrict__ h, unsigned short* __restrict__ h_bf)
{
    __shared__ __align__(16) unsigned short As[32 * 32];
    __shared__ float redS[4][32];
    __shared__ float redS2[4][32];
    const int tid = threadIdx.x;
    const int lane = tid & 63, wave = tid >> 6;
    const int quad = lane >> 4, l16 = lane & 15;
    const int wn = wave * 64;
    const int m0 = blockIdx.x * 32;
    f32x4 acc[2][4] = {};

    for (int k0 = 0; k0 < 256; k0 += 32) {
        {
            int r = tid >> 3, kg = (tid & 7) * 4;
            *(ushort4*)&As[r * 32 + kg] =
                *(const ushort4*)(A + (size_t)(m0 + r) * 256 + k0 + kg);
        }
        __syncthreads();
        short8 bfr[4];
#pragma unroll
        for (int j = 0; j < 4; j++)
            bfr[j] = *(const short8*)(W + (size_t)(wn + j * 16 + l16) * 256 + k0 + quad * 8);
#pragma unroll
        for (int i = 0; i < 2; i++) {
            short8 af = *(const short8*)&As[(i * 16 + l16) * 32 + quad * 8];
#pragma unroll
            for (int j = 0; j < 4; j++)
                acc[i][j] = __builtin_amdgcn_mfma_f32_16x16x32_bf16(af, bfr[j], acc[i][j], 0, 0, 0);
        }
        __syncthreads();
    }

    float bj[4], g1j[4], b1j[4];
#pragma unroll
    for (int j = 0; j < 4; j++) {
        int col = wn + j * 16 + l16;
        bj[j] = bias[col];
        g1j[j] = g1[col]; b1j[j] = b1[col];
    }

#pragma unroll
    for (int i = 0; i < 2; i++)
#pragma unroll
        for (int rg = 0; rg < 4; rg++) {
            int rl = i * 16 + quad * 4 + rg;
#pragma unroll
            for (int j = 0; j < 4; j++) {
                int col = wn + j * 16 + l16;
                acc[i][j][rg] += bj[j] + h[(size_t)(m0 + rl) * 256 + col];
            }
        }
#pragma unroll
    for (int i = 0; i < 2; i++)
#pragma unroll
        for (int rg = 0; rg < 4; rg++) {
            float p = 0.0f, q = 0.0f;
#pragma unroll
            for (int j = 0; j < 4; j++) {
                float v = acc[i][j][rg];
                p += v; q += v * v;
            }
            p = sum16(p);
            q = sum16(q);
            if (l16 == 0) {
                int rl = i * 16 + quad * 4 + rg;
                redS[wave][rl] = p;
                redS2[wave][rl] = q;
            }
        }
    __syncthreads();
#pragma unroll
    for (int i = 0; i < 2; i++)
#pragma unroll
        for (int rg = 0; rg < 4; rg++) {
            int rl = i * 16 + quad * 4 + rg;
            float s = redS[0][rl] + redS[1][rl] + redS[2][rl] + redS[3][rl];
            float qq = redS2[0][rl] + redS2[1][rl] + redS2[2][rl] + redS2[3][rl];
            float mean = s * (1.0f / 256.0f);
            float rstd = 1.0f / sqrtf(qq * (1.0f / 256.0f) - mean * mean + 1e-5f);
            size_t orow = (size_t)(m0 + rl) * 256;
            float y0 = (acc[i][0][rg] - mean) * rstd * g1j[0] + b1j[0];
            float y1 = (acc[i][1][rg] - mean) * rstd * g1j[1] + b1j[1];
            float y2 = (acc[i][2][rg] - mean) * rstd * g1j[2] + b1j[2];
            float y3 = (acc[i][3][rg] - mean) * rstd * g1j[3] + b1j[3];
            h[orow + wn + l16]      = y0;
            h[orow + wn + 16 + l16] = y1;
            h[orow + wn + 32 + l16] = y2;
            h[orow + wn + 48 + l16] = y3;
            unsigned int pA = cvt_pk_bf16(y0, y1);
            unsigned int pB = cvt_pk_bf16(y2, y3);
            unsigned short* hb = h_bf + orow + wn + l16;
            hb[0]  = (unsigned short)pA;
            hb[16] = (unsigned short)(pA >> 16);
            hb[32] = (unsigned short)pB;
            hb[48] = (unsigned short)(pB >> 16);
        }
}

// ================= fused QKV projection + MFMA attention =================
// One block per graph. Wave w handles heads {w, w+4} in 2 passes.
__global__ __launch_bounds__(256) void qkv_attn_kernel(
    const unsigned short* __restrict__ hB, const unsigned short* __restrict__ W,
    const float* __restrict__ bias, unsigned short* __restrict__ o)
{
    __shared__ __align__(16) unsigned short As[64 * 32];       // 4 KB
    __shared__ __align__(16) unsigned short scr[4][5120];      // 40 KB: q(64x40)+k(64x40) / P(64x72)
    __shared__ __align__(16) unsigned short vtS[4][32 * 72];   // 18.4 KB
    const int g = blockIdx.x;
    const int tid = threadIdx.x;
    const int lane = tid & 63, wave = tid >> 6;
    const int quad = lane >> 4, l16 = lane & 15;
    const int m0 = g * 64;
    const int rbase = lane >> 2;
    const int kk = (lane & 3) * 8;
    const float scale = 0.17677669529663687f;   // 1/sqrt(32)

#pragma unroll
    for (int s = 0; s < 2; s++) {
        const int hh = wave + s * 4;
        f32x4 acc[4][6];
#pragma unroll
        for (int i = 0; i < 4; i++)
#pragma unroll
            for (int jt = 0; jt < 6; jt++) acc[i][jt] = (f32x4){0.f, 0.f, 0.f, 0.f};

        for (int k0 = 0; k0 < 256; k0 += 32) {
            {
                int r = wave * 16 + rbase;
                async_copy16(hB + (size_t)(m0 + r) * 256 + k0 + kk, &As[wave * 512 + lane * 8]);
            }
            __syncthreads();
            short8 af[4], bfr[6];
#pragma unroll
            for (int jt = 0; jt < 6; jt++) {
                int n = (jt >> 1) * 256 + hh * 32 + (jt & 1) * 16 + l16;
                bfr[jt] = *(const short8*)(W + (size_t)n * 256 + k0 + quad * 8);
            }
#pragma unroll
            for (int i = 0; i < 4; i++)
                af[i] = *(const short8*)&As[(i * 16 + l16) * 32 + quad * 8];
#pragma unroll
            for (int i = 0; i < 4; i++)
#pragma unroll
                for (int jt = 0; jt < 6; jt++)
                    acc[i][jt] = __builtin_amdgcn_mfma_f32_16x16x32_bf16(af[i], bfr[jt], acc[i][jt], 0, 0, 0);
            __syncthreads();
        }

        // epilogue: q,k -> scr (stride 40), v -> vtS transposed (stride 72)
        unsigned short* qb = &scr[wave][0];
        unsigned short* kb = &scr[wave][2560];
#pragma unroll
        for (int seg = 0; seg < 3; seg++) {
            float bi0 = bias[seg * 256 + hh * 32 + l16];
            float bi1 = bias[seg * 256 + hh * 32 + 16 + l16];
#pragma unroll
            for (int i = 0; i < 4; i++)
#pragma unroll
                for (int rg = 0; rg < 4; rg++) {
                    int row = i * 16 + quad * 4 + rg;
                    unsigned int pk = cvt_pk_bf16(acc[i][seg * 2][rg] + bi0,
                                                  acc[i][seg * 2 + 1][rg] + bi1);
                    unsigned short lo = (unsigned short)pk;
                    unsigned short hi = (unsigned short)(pk >> 16);
                    if (seg == 0)      { qb[row * 40 + l16] = lo; qb[row * 40 + 16 + l16] = hi; }
                    else if (seg == 1) { kb[row * 40 + l16] = lo; kb[row * 40 + 16 + l16] = hi; }
                    else { vtS[wave][l16 * 72 + row] = lo; vtS[wave][(16 + l16) * 72 + row] = hi; }
                }
        }
        // load Q/K frags before P overwrites scr
        short8 aq[4], bk[4];
#pragma unroll
        for (int i = 0; i < 4; i++)
            aq[i] = *(const short8*)&qb[(i * 16 + l16) * 40 + quad * 8];
#pragma unroll
        for (int j = 0; j < 4; j++)
            bk[j] = *(const short8*)&kb[(j * 16 + l16) * 40 + quad * 8];
        __asm__ __volatile__("s_waitcnt lgkmcnt(0)" ::: "memory");

        // S = Q @ K^T
        f32x4 sc[4][4];
#pragma unroll
        for (int i = 0; i < 4; i++)
#pragma unroll
            for (int j = 0; j < 4; j++) sc[i][j] = (f32x4){0.f, 0.f, 0.f, 0.f};
#pragma unroll
        for (int i = 0; i < 4; i++)
#pragma unroll
            for (int j = 0; j < 4; j++)
                sc[i][j] = __builtin_amdgcn_mfma_f32_16x16x32_bf16(aq[i], bk[j], sc[i][j], 0, 0, 0);
        // softmax -> P in scr (stride 72)
        unsigned short* pb = &scr[wave][0];
#pragma unroll
        for (int i = 0; i < 4; i++)
#pragma unroll
            for (int rg = 0; rg < 4; rg++) {
                float v[4];
                float mx = -1e30f;
#pragma unroll
                for (int j = 0; j < 4; j++) {
                    v[j] = sc[i][j][rg] * scale;
                    mx = fmaxf(mx, v[j]);
                }
                mx = max16(mx);
                float sum = 0.0f;
#pragma unroll
                for (int j = 0; j < 4; j++) {
                    v[j] = exp_f(v[j] - mx);
                    sum += v[j];
                }
                sum = sum16(sum);
                float inv = __builtin_amdgcn_rcpf(sum);
                int row = i * 16 + quad * 4 + rg;
                unsigned int pA = cvt_pk_bf16(v[0] * inv, v[1] * inv);
                unsigned int pB = cvt_pk_bf16(v[2] * inv, v[3] * inv);
                unsigned short* pr = &pb[row * 72 + l16];
                pr[0]  = (unsigned short)pA;
                pr[16] = (unsigned short)(pA >> 16);
                pr[32] = (unsigned short)pB;
                pr[48] = (unsigned short)(pB >> 16);
            }
        // O = P @ V
        f32x4 oc[4][2];
#pragma unroll
        for (int i = 0; i < 4; i++)
#pragma unroll
            for (int j = 0; j < 2; j++) oc[i][j] = (f32x4){0.f, 0.f, 0.f, 0.f};
#pragma unroll
        for (int k0 = 0; k0 < 64; k0 += 32) {
            short8 ap[4], bv[2];
#pragma unroll
            for (int i = 0; i < 4; i++)
                ap[i] = *(const short8*)&pb[(i * 16 + l16) * 72 + k0 + quad * 8];
#pragma unroll
            for (int j = 0; j < 2; j++)
                bv[j] = *(const short8*)&vtS[wave][(j * 16 + l16) * 72 + k0 + quad * 8];
#pragma unroll
            for (int i = 0; i < 4; i++)
#pragma unroll
                for (int j = 0; j < 2; j++)
                    oc[i][j] = __builtin_amdgcn_mfma_f32_16x16x32_bf16(ap[i], bv[j], oc[i][j], 0, 0, 0);
        }
#pragma unroll
        for (int i = 0; i < 4; i++)
#pragma unroll
            for (int rg = 0; rg < 4; rg++) {
                int row = i * 16 + quad * 4 + rg;
                unsigned short* ob = o + (size_t)(m0 + row) * 256 + hh * 32;
                unsigned int pk = cvt_pk_bf16(oc[i][0][rg], oc[i][1][rg]);
                ob[l16]      = (unsigned short)pk;
                ob[16 + l16] = (unsigned short)(pk >> 16);
            }
    }
}

extern "C" void kernel_launch(void* const* d_in, const int* in_sizes, int n_in,
                              void* d_out, int out_size, void* d_ws, size_t ws_size,
                              hipStream_t stream)
{
    const float* x    = (const float*)d_in[0];
    const float* pos  = (const float*)d_in[1];
    const int*   ei   = (const int*)d_in[2];
    const float* pe_w1 = (const float*)d_in[5];
    const float* pe_b1 = (const float*)d_in[6];
    const float* pe_w2 = (const float*)d_in[7];
    const float* pe_b2 = (const float*)d_in[8];
    const float* pe_lg = (const float*)d_in[9];
    const float* pe_lb = (const float*)d_in[10];
    const float* ph_w1 = (const float*)d_in[11];
    const float* ph_b1 = (const float*)d_in[12];
    const float* ph_w2 = (const float*)d_in[13];
    const float* ph_b2 = (const float*)d_in[14];
    const float* ph_lg = (const float*)d_in[15];
    const float* ph_lb = (const float*)d_in[16];
    const float* px_w1 = (const float*)d_in[17];
    const float* px_b1 = (const float*)d_in[18];
    const float* px_w2 = (const float*)d_in[19];
    const float* px_b2 = (const float*)d_in[20];
    const float* ain_w = (const float*)d_in[21];
    const float* ain_b = (const float*)d_in[22];
    const float* aout_w = (const float*)d_in[23];
    const float* aout_b = (const float*)d_in[24];
    const float* lnh_g = (const float*)d_in[25];
    const float* lnh_b = (const float*)d_in[26];
    const float* lna_g = (const float*)d_in[27];
    const float* lna_b = (const float*)d_in[28];
    const float* ff_w1 = (const float*)d_in[29];
    const float* ff_b1 = (const float*)d_in[30];
    const float* ff_w2 = (const float*)d_in[31];
    const float* ff_b2 = (const float*)d_in[32];
    const float* ps    = (const float*)d_in[33];

    char* p = (char*)d_ws;
    auto alloc = [&](size_t bytes) { char* r = p; p += (bytes + 63) & ~(size_t)63; return r; };
    float* h      = (float*)alloc((size_t)NTOTC * HC * 4);
    unsigned short* h_bf  = (unsigned short*)alloc((size_t)NTOTC * HC * 2);
    unsigned short* xcat_bf = (unsigned short*)alloc((size_t)NTOTC * 512 * 2);
    float* cur    = (float*)alloc((size_t)NTOTC * 3 * 4);
    float* posupd = (float*)alloc((size_t)NTOTC * 3 * 4);
    float* hmsg   = (float*)alloc((size_t)NTOTC * HC * 4);
    unsigned short* o_bf   = (unsigned short*)alloc((size_t)NTOTC * HC * 2);
    unsigned short* ff1_bf = (unsigned short*)alloc((size_t)NTOTC * 4 * HC * 2);
    int* cnt  = (int*)alloc(16384 * 4);
    int* ptrw = (int*)alloc(16384 * 4);
    int* rowP = (int*)alloc((size_t)NEDGEC * 4);
    int* colP = (int*)alloc((size_t)NEDGEC * 4);
    float* zbias = (float*)alloc(512 * 4);
    unsigned short* w_pe1s = (unsigned short*)alloc((size_t)LC * 512 * 256 * 2);
    float*          w_last = (float*)alloc((size_t)LC * 256 * 4);
    unsigned short* w_pe2  = (unsigned short*)alloc((size_t)LC * 256 * 256 * 2);
    unsigned short* w_ph1  = (unsigned short*)alloc((size_t)LC * 256 * 256 * 2);
    unsigned short* w_ph2  = (unsigned short*)alloc((size_t)LC * 256 * 256 * 2);
    unsigned short* w_px1  = (unsigned short*)alloc((size_t)LC * 256 * 256 * 2);
    unsigned short* w_ain  = (unsigned short*)alloc((size_t)LC * 768 * 256 * 2);
    unsigned short* w_aout = (unsigned short*)alloc((size_t)LC * 256 * 256 * 2);
    unsigned short* w_ff1  = (unsigned short*)alloc((size_t)LC * 1024 * 256 * 2);
    unsigned short* w_ff2  = (unsigned short*)alloc((size_t)LC * 256 * 1024 * 2);

    // ---- counting sort of edges by col ----
    hipMemsetAsync(cnt, 0, 16384 * 4, stream);
    hipMemsetAsync(zbias, 0, 512 * 4, stream);
    hist_kernel<<<NEDGEC / 256, 256, 0, stream>>>(ei + NEDGEC, cnt);
    scan16k_kernel<<<1, 256, 0, stream>>>(cnt, ptrw);
    permute_kernel<<<NEDGEC / 256, 256, 0, stream>>>(ei, ei + NEDGEC, ptrw, rowP, colP);

    // ---- convert weights to bf16 ----
    conv_pe1_kernel<<<(LC * 256 * 513 + 255) / 256, 256, 0, stream>>>(pe_w1, w_pe1s, w_last);
    conv_bf16_kernel<<<1536, 256, 0, stream>>>(pe_w2, w_pe2, LC * 256 * 256);
    conv_bf16_kernel<<<1536, 256, 0, stream>>>(ph_w1, w_ph1, LC * 256 * 256);
    conv_bf16_kernel<<<1536, 256, 0, stream>>>(ph_w2, w_ph2, LC * 256 * 256);
    conv_bf16_kernel<<<1536, 256, 0, stream>>>(px_w1, w_px1, LC * 256 * 256);
    conv_bf16_kernel<<<4608, 256, 0, stream>>>(ain_w, w_ain, LC * 768 * 256);
    conv_bf16_kernel<<<1536, 256, 0, stream>>>(aout_w, w_aout, LC * 256 * 256);
    conv_bf16_kernel<<<6144, 256, 0, stream>>>(ff_w1, w_ff1, LC * 1024 * 256);
    conv_bf16_kernel<<<6144, 256, 0, stream>>>(ff_w2, w_ff2, LC * 256 * 1024);

    hipMemcpyAsync(h, x, (size_t)NTOTC * HC * 4, hipMemcpyDeviceToDevice, stream);
    hipMemcpyAsync(cur, pos, (size_t)NTOTC * 3 * 4, hipMemcpyDeviceToDevice, stream);
    conv_bf16_kernel<<<4096, 256, 0, stream>>>(x, h_bf, NTOTC * HC);
    // zero accumulators once; per-layer re-zero is fused into phi_h
    hipMemsetAsync(hmsg, 0, (size_t)NTOTC * HC * 4, stream);
    hipMemsetAsync(posupd, 0, (size_t)NTOTC * 3 * 4, stream);

    for (int l = 0; l < LC; l++) {
        // xcat = h @ [W1a;W1b]^T   (MT=64: 1024 blocks, 4/CU)
        mgemm_kernel<64, 0, false, false, true><<<dim3(NTOTC / 64, 4), 256, 0, stream>>>(
            h_bf, w_pe1s + (size_t)l * 512 * 256, zbias,
            nullptr, nullptr, xcat_bf, NTOTC, 512, HC);

        fused_edge_kernel<<<NEDGEC / 64, 256, 0, stream>>>(
            xcat_bf, cur, rowP, colP,
            w_last + (size_t)l * 256, pe_b1 + (size_t)l * HC,
            w_pe2 + (size_t)l * 256 * 256, pe_b2 + (size_t)l * HC,
            pe_lg + (size_t)l * HC, pe_lb + (size_t)l * HC,
            w_px1 + (size_t)l * 256 * 256, px_b1 + (size_t)l * HC,
            px_w2 + (size_t)l * HC, px_b2 + l,
            hmsg, posupd);

        // phi_h fully fused (+ cur update + posupd/hmsg re-zero); M=32 grid
        phi_h_fused_kernel<<<NTOTC / 32, 256, 0, stream>>>(
            h, hmsg,
            w_ph1 + (size_t)l * 256 * 256, ph_b1 + (size_t)l * HC,
            w_ph2 + (size_t)l * 256 * 256, ph_b2 + (size_t)l * HC,
            ph_lg + (size_t)l * HC, ph_lb + (size_t)l * HC,
            lnh_g + (size_t)l * HC, lnh_b + (size_t)l * HC, h, h_bf,
            cur, posupd, ps, l);

        // fused qkv projection + attention
        qkv_attn_kernel<<<NTOTC / 64, 256, 0, stream>>>(
            h_bf, w_ain + (size_t)l * 768 * 256, ain_b + (size_t)l * 3 * HC, o_bf);
        node_fused_kernel<<<NTOTC / 32, 256, 0, stream>>>(
            o_bf, w_aout + (size_t)l * 256 * 256, aout_b + (size_t)l * HC,
            lna_g + (size_t)l * HC, lna_b + (size_t)l * HC, h, h_bf);

        // feed-forward with residual
        mgemm_kernel<128, 2, false, false, true><<<dim3(NTOTC / 128, 8), 256, 0, stream>>>(
            h_bf, w_ff1 + (size_t)l * 1024 * 256, ff_b1 + (size_t)l * 4 * HC,
            nullptr, nullptr, ff1_bf, NTOTC, 4 * HC, HC);
        mgemm_kernel<64, 0, true, true, true><<<dim3(NTOTC / 64, 2), 256, 0, stream>>>(
            ff1_bf, w_ff2 + (size_t)l * 256 * 1024, ff_b2 + (size_t)l * HC,
            h, h, h_bf, NTOTC, HC, 4 * HC);
    }

    hipMemcpyAsync(d_out, h, (size_t)NTOTC * HC * 4, hipMemcpyDeviceToDevice, stream);
    hipMemcpyAsync((float*)d_out + (size_t)NTOTC * HC, cur, (size_t)NTOTC * 3 * 4,
                   hipMemcpyDeviceToDevice, stream);
}

// Round 13
// 2058.786 us; speedup vs baseline: 1.0069x; 1.0069x over previous
//
#include <hip/hip_runtime.h>
#include <cstddef>
#include <cstdint>

#define NTOTC 16384
#define HC 256
#define LC 6
#define NEDGEC 262144
#define NHEADSC 8

typedef __attribute__((ext_vector_type(8))) short short8;
typedef __attribute__((ext_vector_type(4))) float f32x4;

__device__ __forceinline__ unsigned short f2bf(float f) {
    unsigned int u = __float_as_uint(f);
    u += 0x7fff + ((u >> 16) & 1);   // round-to-nearest-even
    return (unsigned short)(u >> 16);
}
__device__ __forceinline__ float bf2f(unsigned short s) {
    return __uint_as_float(((unsigned int)s) << 16);
}
// packed f32x2 -> bf16x2 (RTNE, identical rounding to f2bf); 1 instr for 2 elems
__device__ __forceinline__ unsigned int cvt_pk_bf16(float lo, float hi) {
    unsigned int r;
    asm("v_cvt_pk_bf16_f32 %0, %1, %2" : "=v"(r) : "v"(lo), "v"(hi));
    return r;
}
__device__ __forceinline__ void async_copy16(const void* g, void* l) {
    __builtin_amdgcn_global_load_lds(
        (const __attribute__((address_space(1))) unsigned int*)g,
        (__attribute__((address_space(3))) unsigned int*)l, 16, 0, 0);
}
// fast transcendentals; ~1e-6 rel err, negligible vs bf16
__device__ __forceinline__ float exp_f(float v) {
    return __builtin_amdgcn_exp2f(v * 1.4426950408889634f);
}
__device__ __forceinline__ float silu_f(float v) {
    return v * __builtin_amdgcn_rcpf(1.0f + __builtin_amdgcn_exp2f(-v * 1.4426950408889634f));
}
__device__ __forceinline__ float tanh_f(float v) {
    float e = __builtin_amdgcn_exp2f(v * 2.8853900817779268f);   // e^(2v)
    return 1.0f - 2.0f * __builtin_amdgcn_rcpf(1.0f + e);
}

// ---- DPP 16-lane reductions (VALU, no LDS pipe; tree identical to shfl_xor 1,2,4,8) ----
template<int CTRL>
__device__ __forceinline__ float dpp_movf(float x) {
    return __int_as_float(__builtin_amdgcn_update_dpp(
        0, __float_as_int(x), CTRL, 0xF, 0xF, true));
}
__device__ __forceinline__ float sum16(float x) {
    x += dpp_movf<0xB1>(x);    // quad_perm [1,0,3,2]  (xor 1)
    x += dpp_movf<0x4E>(x);    // quad_perm [2,3,0,1]  (xor 2)
    x += dpp_movf<0x141>(x);   // row_half_mirror      (xor 4 equiv.)
    x += dpp_movf<0x140>(x);   // row_mirror           (xor 8 equiv.)
    return x;
}
__device__ __forceinline__ float max16(float x) {
    x = fmaxf(x, dpp_movf<0xB1>(x));
    x = fmaxf(x, dpp_movf<0x4E>(x));
    x = fmaxf(x, dpp_movf<0x141>(x));
    x = fmaxf(x, dpp_movf<0x140>(x));
    return x;
}

// ================= weight conversion =================
__global__ __launch_bounds__(256) void conv_bf16_kernel(
    const float* __restrict__ in, unsigned short* __restrict__ out, int n)
{
    int n4 = n >> 2;   // all call sites have n % 4 == 0
    for (int i = blockIdx.x * 256 + threadIdx.x; i < n4; i += gridDim.x * 256) {
        float4 v = ((const float4*)in)[i];
        ((uint2*)out)[i] = make_uint2(cvt_pk_bf16(v.x, v.y), cvt_pk_bf16(v.z, v.w));
    }
}

// phi_e_w1 [L,256,513] -> stacked bf16 [L,512,256] ([W1a;W1b]) + fp32 dist column [L,256]
__global__ __launch_bounds__(256) void conv_pe1_kernel(
    const float* __restrict__ in, unsigned short* __restrict__ outk, float* __restrict__ wlast)
{
    int idx = blockIdx.x * 256 + threadIdx.x;
    if (idx >= LC * 256 * 513) return;
    int l = idx / (256 * 513);
    int rem = idx % (256 * 513);
    int n = rem / 513;
    int k = rem % 513;
    float v = in[idx];
    if (k == 512) wlast[l * 256 + n] = v;
    else if (k < 256) outk[(size_t)l * 512 * 256 + (size_t)n * 256 + k] = f2bf(v);
    else outk[(size_t)l * 512 * 256 + (size_t)(256 + n) * 256 + (k - 256)] = f2bf(v);
}

// ================= counting sort of edges by col =================
__global__ __launch_bounds__(256) void hist_kernel(
    const int* __restrict__ col, int* __restrict__ cnt)
{
    int e = blockIdx.x * 256 + threadIdx.x;
    atomicAdd(&cnt[col[e]], 1);
}

__global__ __launch_bounds__(256) void scan16k_kernel(
    const int* __restrict__ cnt, int* __restrict__ ptrw)
{
    __shared__ int partial[256];
    const int t = threadIdx.x;
    const int base = t * 64;
    int loc[64];
    int s = 0;
#pragma unroll
    for (int i = 0; i < 64; i++) { loc[i] = s; s += cnt[base + i]; }
    partial[t] = s;
    __syncthreads();
    if (t == 0) {
        int run = 0;
        for (int i = 0; i < 256; i++) { int tmp = partial[i]; partial[i] = run; run += tmp; }
    }
    __syncthreads();
    int off = partial[t];
#pragma unroll
    for (int i = 0; i < 64; i++) ptrw[base + i] = off + loc[i];
}

__global__ __launch_bounds__(256) void permute_kernel(
    const int* __restrict__ row, const int* __restrict__ col, int* __restrict__ ptrw,
    int* __restrict__ rowP, int* __restrict__ colP)
{
    int e = blockIdx.x * 256 + threadIdx.x;
    int c = col[e];
    int pos = atomicAdd(&ptrw[c], 1);
    rowP[pos] = row[e];
    colP[pos] = c;
}

// ================= generic MFMA GEMM: C = act(A @ W^T + bias)(+R) =================
// MT = M-tile (128 or 64). Block tile = MT x 128, 4 waves.
template<int MT, int ACT, bool RES, bool WF, bool WB>
__global__ __launch_bounds__(256) void mgemm_kernel(
    const unsigned short* __restrict__ A, const unsigned short* __restrict__ W,
    const float* __restrict__ bias, const float* __restrict__ R,
    float* __restrict__ Cf, unsigned short* __restrict__ Cb,
    int M, int N, int K)
{
    constexpr int FI = MT / 32;            // M-fragments per wave (4 or 2)
    __shared__ unsigned short As[MT * 32];
    __shared__ unsigned short Bs[128 * 32];
    const int tid = threadIdx.x;
    const int lane = tid & 63, wave = tid >> 6;
    const int quad = lane >> 4, l16 = lane & 15;
    const int wm = (wave >> 1) * (MT / 2), wn = (wave & 1) * 64;
    const int m0 = blockIdx.x * MT, n0 = blockIdx.y * 128;
    f32x4 acc[FI][4] = {};
    const int rbase = (lane >> 2);
    const int kk = (lane & 3) * 8;

    for (int k0 = 0; k0 < K; k0 += 32) {
#pragma unroll
        for (int c = 0; c < MT / 64; c++) {
            int t = wave * (MT / 64) + c;
            int r = t * 16 + rbase;
            async_copy16(A + (size_t)(m0 + r) * K + k0 + kk, &As[t * 512 + lane * 8]);
        }
#pragma unroll
        for (int c = 0; c < 2; c++) {
            int t = wave * 2 + c;
            int r = t * 16 + rbase;
            async_copy16(W + (size_t)(n0 + r) * K + k0 + kk, &Bs[t * 512 + lane * 8]);
        }
        __syncthreads();
        short8 af[FI], bfr[4];
#pragma unroll
        for (int i = 0; i < FI; i++)
            af[i] = *(const short8*)&As[(wm + i * 16 + l16) * 32 + quad * 8];
#pragma unroll
        for (int j = 0; j < 4; j++)
            bfr[j] = *(const short8*)&Bs[(wn + j * 16 + l16) * 32 + quad * 8];
#pragma unroll
        for (int i = 0; i < FI; i++)
#pragma unroll
            for (int j = 0; j < 4; j++)
                acc[i][j] = __builtin_amdgcn_mfma_f32_16x16x32_bf16(af[i], bfr[j], acc[i][j], 0, 0, 0);
        __syncthreads();
    }
#pragma unroll
    for (int jp = 0; jp < 2; jp++) {
        int col0 = n0 + wn + jp * 32 + l16;
        int col1 = col0 + 16;
        float bi0 = bias[col0], bi1 = bias[col1];
#pragma unroll
        for (int i = 0; i < FI; i++) {
#pragma unroll
            for (int rg = 0; rg < 4; rg++) {
                int row = m0 + wm + i * 16 + quad * 4 + rg;
                float v0 = acc[i][jp * 2][rg] + bi0;
                float v1 = acc[i][jp * 2 + 1][rg] + bi1;
                if (ACT == 1) { v0 = silu_f(v0); v1 = silu_f(v1); }
                if (ACT == 2) {
                    v0 = 0.5f * v0 * (1.0f + erff(v0 * 0.7071067811865476f));
                    v1 = 0.5f * v1 * (1.0f + erff(v1 * 0.7071067811865476f));
                }
                if (RES) {
                    v0 += R[(size_t)row * N + col0];
                    v1 += R[(size_t)row * N + col1];
                }
                if (WF) {
                    Cf[(size_t)row * N + col0] = v0;
                    Cf[(size_t)row * N + col1] = v1;
                }
                if (WB) {
                    unsigned int pk = cvt_pk_bf16(v0, v1);
                    Cb[(size_t)row * N + col0] = (unsigned short)pk;
                    Cb[(size_t)row * N + col1] = (unsigned short)(pk >> 16);
                }
            }
        }
    }
}

// ================= FUSED edge pipeline (M=64, rel/dist inline) =================
__global__ __launch_bounds__(256, 4) void fused_edge_kernel(
    const unsigned short* __restrict__ xcat, const float* __restrict__ cur,
    const int* __restrict__ rowP, const int* __restrict__ colP,
    const float* __restrict__ wlast, const float* __restrict__ b1,
    const unsigned short* __restrict__ W2, const float* __restrict__ b2,
    const float* __restrict__ lg, const float* __restrict__ lb,
    const unsigned short* __restrict__ W3, const float* __restrict__ b3,
    const float* __restrict__ w2v, const float* __restrict__ b2s,
    float* __restrict__ hmsg, float* __restrict__ posupd)
{
    __shared__ __align__(16) unsigned short tS[64 * 264];
    __shared__ float redS[4][64];
    __shared__ float redS2[4][64];
    __shared__ int rowS[64], colS[64], flagS[64];
    __shared__ float distS[64];
    __shared__ float relS[64][3];
    __shared__ float cfS[64];
    __shared__ int openS[2];   // [0]: first col continues from prev block; [1]: last col continues into next

    const int tid = threadIdx.x;
    const int lane = tid & 63, wave = tid >> 6;
    const int quad = lane >> 4, l16 = lane & 15;
    const int wn = wave * 64;
    const int m0 = blockIdx.x * 64;

    if (tid < 64) {
        int r = rowP[m0 + tid];
        int c = colP[m0 + tid];
        rowS[tid] = r;
        colS[tid] = c;
        float rx = cur[(size_t)r * 3 + 0] - cur[(size_t)c * 3 + 0];
        float ry = cur[(size_t)r * 3 + 1] - cur[(size_t)c * 3 + 1];
        float rz = cur[(size_t)r * 3 + 2] - cur[(size_t)c * 3 + 2];
        relS[tid][0] = rx;
        relS[tid][1] = ry;
        relS[tid][2] = rz;
        float dx = rx + 1e-8f, dy = ry + 1e-8f, dz = rz + 1e-8f;  // ref adds eps per component
        distS[tid] = sqrtf(dx * dx + dy * dy + dz * dz);
    }
    if (tid == 64) {
        openS[0] = (m0 > 0) && (colP[m0 - 1] == colP[m0]);
        openS[1] = (m0 + 64 < NEDGEC) && (colP[m0 + 64] == colP[m0 + 63]);
    }
    __syncthreads();
    if (tid < 64) flagS[tid] = (tid == 63) || (colS[tid] != colS[tid + 1]);

    // ---- Stage 1: gather-add replacing edge GEMM1 (16B vectorized) ----
    {
        const int half = lane >> 5;          // 0/1: which of the wave's 2 rows
        const int cb = (lane & 31) * 8;      // 8 adjacent cols per lane (16B)
        float4 wlA = *(const float4*)&wlast[cb];
        float4 wlB = *(const float4*)&wlast[cb + 4];
        float4 b1A = *(const float4*)&b1[cb];
        float4 b1B = *(const float4*)&b1[cb + 4];
#pragma unroll
        for (int rr = 0; rr < 8; rr++) {
            int r = rr * 8 + wave * 2 + half;
            const short8 ua = *(const short8*)(xcat + (size_t)rowS[r] * 512 + cb);
            const short8 ub = *(const short8*)(xcat + (size_t)colS[r] * 512 + 256 + cb);
            float dv = distS[r];
            float v0 = bf2f((unsigned short)ua[0]) + bf2f((unsigned short)ub[0]) + dv * wlA.x + b1A.x;
            float v1 = bf2f((unsigned short)ua[1]) + bf2f((unsigned short)ub[1]) + dv * wlA.y + b1A.y;
            float v2 = bf2f((unsigned short)ua[2]) + bf2f((unsigned short)ub[2]) + dv * wlA.z + b1A.z;
            float v3 = bf2f((unsigned short)ua[3]) + bf2f((unsigned short)ub[3]) + dv * wlA.w + b1A.w;
            float v4 = bf2f((unsigned short)ua[4]) + bf2f((unsigned short)ub[4]) + dv * wlB.x + b1B.x;
            float v5 = bf2f((unsigned short)ua[5]) + bf2f((unsigned short)ub[5]) + dv * wlB.y + b1B.y;
            float v6 = bf2f((unsigned short)ua[6]) + bf2f((unsigned short)ub[6]) + dv * wlB.z + b1B.z;
            float v7 = bf2f((unsigned short)ua[7]) + bf2f((unsigned short)ub[7]) + dv * wlB.w + b1B.w;
            uint4 o;
            o.x = cvt_pk_bf16(silu_f(v0), silu_f(v1));
            o.y = cvt_pk_bf16(silu_f(v2), silu_f(v3));
            o.z = cvt_pk_bf16(silu_f(v4), silu_f(v5));
            o.w = cvt_pk_bf16(silu_f(v6), silu_f(v7));
            *(uint4*)&tS[r * 264 + cb] = o;
        }
    }
    __syncthreads();

    f32x4 acc[4][4];

    // ---- GEMM2: K=256, A from tS, W2 direct; NO barriers in k-loop ----
#pragma unroll
    for (int i = 0; i < 4; i++)
#pragma unroll
        for (int j = 0; j < 4; j++) acc[i][j] = (f32x4){0.f, 0.f, 0.f, 0.f};
#pragma unroll
    for (int k0 = 0; k0 < 256; k0 += 32) {
        short8 af[4], bfr[4];
#pragma unroll
        for (int j = 0; j < 4; j++)
            bfr[j] = *(const short8*)(W2 + (size_t)(wn + j * 16 + l16) * 256 + k0 + quad * 8);
#pragma unroll
        for (int i = 0; i < 4; i++)
            af[i] = *(const short8*)&tS[(i * 16 + l16) * 264 + k0 + quad * 8];
#pragma unroll
        for (int i = 0; i < 4; i++)
#pragma unroll
            for (int j = 0; j < 4; j++)
                acc[i][j] = __builtin_amdgcn_mfma_f32_16x16x32_bf16(af[i], bfr[j], acc[i][j], 0, 0, 0);
    }
    __syncthreads();
    // epilogue 2: LN -> m -> tS (overwrite)
    {
        float b2j[4], gj[4], bbj[4];
#pragma unroll
        for (int j = 0; j < 4; j++) {
            int col = wn + j * 16 + l16;
            b2j[j] = b2[col];
            gj[j] = lg[col];
            bbj[j] = lb[col];
        }
        // fold bias into acc once (used by both reduce and write passes)
#pragma unroll
        for (int i = 0; i < 4; i++)
#pragma unroll
            for (int j = 0; j < 4; j++)
#pragma unroll
                for (int rg = 0; rg < 4; rg++) acc[i][j][rg] += b2j[j];
#pragma unroll
        for (int i = 0; i < 4; i++)
#pragma unroll
            for (int rg = 0; rg < 4; rg++) {
                float p = 0.0f, q = 0.0f;
#pragma unroll
                for (int j = 0; j < 4; j++) {
                    float v = acc[i][j][rg];
                    p += v; q += v * v;
                }
                p = sum16(p);
                q = sum16(q);
                if (l16 == 0) {
                    int row = i * 16 + quad * 4 + rg;
                    redS[wave][row] = p;
                    redS2[wave][row] = q;
                }
            }
        __syncthreads();
#pragma unroll
        for (int i = 0; i < 4; i++)
#pragma unroll
            for (int rg = 0; rg < 4; rg++) {
                int row = i * 16 + quad * 4 + rg;
                float s = redS[0][row] + redS[1][row] + redS[2][row] + redS[3][row];
                float qq = redS2[0][row] + redS2[1][row] + redS2[2][row] + redS2[3][row];
                float mean = s * (1.0f / 256.0f);
                float rstd = 1.0f / sqrtf(qq * (1.0f / 256.0f) - mean * mean + 1e-5f);
                float y0 = (acc[i][0][rg] - mean) * rstd * gj[0] + bbj[0];
                float y1 = (acc[i][1][rg] - mean) * rstd * gj[1] + bbj[1];
                float y2 = (acc[i][2][rg] - mean) * rstd * gj[2] + bbj[2];
                float y3 = (acc[i][3][rg] - mean) * rstd * gj[3] + bbj[3];
                unsigned int pA = cvt_pk_bf16(y0, y1);
                unsigned int pB = cvt_pk_bf16(y2, y3);
                unsigned short* tb = &tS[row * 264 + wn + l16];
                tb[0]  = (unsigned short)pA;
                tb[16] = (unsigned short)(pA >> 16);
                tb[32] = (unsigned short)pB;
                tb[48] = (unsigned short)(pB >> 16);
            }
    }
    __syncthreads();

    // ---- segmented scatter of m into hmsg: wave w owns cols [64w,64w+64), 1 col/lane ----
    // Flush ONLY at true segment boundaries. Interior segments (wholly contained in this
    // block) are exclusively owned -> plain store (hmsg pre-zeroed). Only the first
    // segment (if continued from prev block) and last (if continued into next) need atomics.
    {
        const int c = wn + lane;             // one column per lane
        const bool openL = openS[0] != 0;
        const bool openR = openS[1] != 0;
        float s = 0.0f;
        bool first = true;
        for (int r = 0; r < 64; r++) {
            s += bf2f(tS[r * 264 + c]);
            if (flagS[r]) {
                float* dst = &hmsg[(size_t)colS[r] * 256 + c];
                bool needAtomic = (first && openL) || (r == 63 && openR);
                if (needAtomic) atomicAdd(dst, s);
                else *dst = s;
                s = 0.0f;
                first = false;
            }
        }
    }

    // ---- GEMM3: K=256, A = m from tS, W3 direct ----
#pragma unroll
    for (int i = 0; i < 4; i++)
#pragma unroll
        for (int j = 0; j < 4; j++) acc[i][j] = (f32x4){0.f, 0.f, 0.f, 0.f};
#pragma unroll
    for (int k0 = 0; k0 < 256; k0 += 32) {
        short8 af[4], bfr[4];
#pragma unroll
        for (int j = 0; j < 4; j++)
            bfr[j] = *(const short8*)(W3 + (size_t)(wn + j * 16 + l16) * 256 + k0 + quad * 8);
#pragma unroll
        for (int i = 0; i < 4; i++)
            af[i] = *(const short8*)&tS[(i * 16 + l16) * 264 + k0 + quad * 8];
#pragma unroll
        for (int i = 0; i < 4; i++)
#pragma unroll
            for (int j = 0; j < 4; j++)
                acc[i][j] = __builtin_amdgcn_mfma_f32_16x16x32_bf16(af[i], bfr[j], acc[i][j], 0, 0, 0);
    }
    // epilogue 3
    {
        float b3j[4], w2j[4];
#pragma unroll
        for (int j = 0; j < 4; j++) {
            int col = wn + j * 16 + l16;
            b3j[j] = b3[col];
            w2j[j] = w2v[col];
        }
#pragma unroll
        for (int i = 0; i < 4; i++)
#pragma unroll
            for (int rg = 0; rg < 4; rg++) {
                float p = 0.0f;
#pragma unroll
                for (int j = 0; j < 4; j++)
                    p += silu_f(acc[i][j][rg] + b3j[j]) * w2j[j];
                p = sum16(p);
                if (l16 == 0) redS[wave][i * 16 + quad * 4 + rg] = p;
            }
        __syncthreads();
        if (tid < 64) {
            float tot = redS[0][tid] + redS[1][tid] + redS[2][tid] + redS[3][tid] + b2s[0];
            cfS[tid] = tanh_f(tot);
        }
        __syncthreads();
        // pos scatter: 12 lanes = 3 components x 4 row-groups (chain 64 -> 16)
        if (tid < 12) {
            const int comp = tid % 3;
            const int gbase = (tid / 3) * 16;
            float s = 0.0f;
#pragma unroll
            for (int rr = 0; rr < 16; rr++) {
                int r = gbase + rr;
                s += relS[r][comp] * cfS[r];
                if (flagS[r] || rr == 15) {
                    atomicAdd(&posupd[(size_t)colS[r] * 3 + comp], s);
                    s = 0.0f;
                }
            }
        }
    }
}

// ============ phi_h fused + cur-update + hmsg re-zero (M=32, direct-B) ============
// h = LN2(h + LN1(silu((h+hmsg)@W1^T+b1)@W2^T+b2)); cur += ps[l]*posupd (posupd zeroed);
// block zeroes its own hmsg rows for the next layer. Grid = NTOT/32.
__global__ __launch_bounds__(256) void phi_h_fused_kernel(
    const float* __restrict__ h_in, float* __restrict__ hmsg,
    const unsigned short* __restrict__ W1, const float* __restrict__ b1v,
    const unsigned short* __restrict__ W2, const float* __restrict__ bias,
    const float* __restrict__ g1, const float* __restrict__ bb1,
    const float* __restrict__ g2, const float* __restrict__ bb2,
    float* __restrict__ h, unsigned short* __restrict__ h_bf,
    float* __restrict__ cur, float* __restrict__ posupd, const float* __restrict__ psv, int l)
{
    __shared__ __align__(16) unsigned short As[32 * 32];
    __shared__ __align__(16) unsigned short tS[32 * 264];
    __shared__ float redS[4][32];
    __shared__ float redS2[4][32];
    const int tid = threadIdx.x;
    const int lane = tid & 63, wave = tid >> 6;
    const int quad = lane >> 4, l16 = lane & 15;
    const int wn = wave * 64;
    const int m0 = blockIdx.x * 32;
    f32x4 acc[2][4] = {};

    // side job: cur += ps[l] * posupd; posupd = 0  (49152 elements over first 192 blocks)
    {
        int e = blockIdx.x * 256 + tid;
        if (e < NTOTC * 3) {
            cur[e] += psv[l] * posupd[e];
            posupd[e] = 0.0f;
        }
    }

    // GEMM1: A = bf16(h+hmsg) staged per k-step; B = W1 direct from L2
    for (int k0 = 0; k0 < 256; k0 += 32) {
        {
            int r = tid >> 3, kg = (tid & 7) * 4;
            float4 a = *(const float4*)&h_in[(size_t)(m0 + r) * 256 + k0 + kg];
            float4 b = *(const float4*)&hmsg[(size_t)(m0 + r) * 256 + k0 + kg];
            unsigned int p0 = cvt_pk_bf16(a.x + b.x, a.y + b.y);
            unsigned int p1 = cvt_pk_bf16(a.z + b.z, a.w + b.w);
            *(uint2*)&As[r * 32 + kg] = make_uint2(p0, p1);
        }
        __syncthreads();
        short8 bfr[4];
#pragma unroll
        for (int j = 0; j < 4; j++)
            bfr[j] = *(const short8*)(W1 + (size_t)(wn + j * 16 + l16) * 256 + k0 + quad * 8);
#pragma unroll
        for (int i = 0; i < 2; i++) {
            short8 af = *(const short8*)&As[(i * 16 + l16) * 32 + quad * 8];
#pragma unroll
            for (int j = 0; j < 4; j++)
                acc[i][j] = __builtin_amdgcn_mfma_f32_16x16x32_bf16(af, bfr[j], acc[i][j], 0, 0, 0);
        }
        __syncthreads();
    }
    // zero this block's hmsg rows (fully consumed above) for the next layer
    {
        size_t base = (size_t)m0 * 256;
        float4 z = {0.f, 0.f, 0.f, 0.f};
#pragma unroll
        for (int t = 0; t < 8; t++)
            *(float4*)&hmsg[base + (size_t)(t * 256 + tid) * 4] = z;
    }
    {
        float b1j[4];
#pragma unroll
        for (int j = 0; j < 4; j++) b1j[j] = b1v[wn + j * 16 + l16];
#pragma unroll
        for (int i = 0; i < 2; i++)
#pragma unroll
            for (int rg = 0; rg < 4; rg++) {
                int row = i * 16 + quad * 4 + rg;
                float s0 = silu_f(acc[i][0][rg] + b1j[0]);
                float s1 = silu_f(acc[i][1][rg] + b1j[1]);
                float s2 = silu_f(acc[i][2][rg] + b1j[2]);
                float s3 = silu_f(acc[i][3][rg] + b1j[3]);
                unsigned int pA = cvt_pk_bf16(s0, s1);
                unsigned int pB = cvt_pk_bf16(s2, s3);
                unsigned short* tb = &tS[row * 264 + wn + l16];
                tb[0]  = (unsigned short)pA;
                tb[16] = (unsigned short)(pA >> 16);
                tb[32] = (unsigned short)pB;
                tb[48] = (unsigned short)(pB >> 16);
            }
    }
    __syncthreads();

    // GEMM2: A = tS, B = W2 direct; no barriers in k-loop
#pragma unroll
    for (int i = 0; i < 2; i++)
#pragma unroll
        for (int j = 0; j < 4; j++) acc[i][j] = (f32x4){0.f, 0.f, 0.f, 0.f};
#pragma unroll
    for (int k0 = 0; k0 < 256; k0 += 32) {
        short8 af[2], bfr[4];
#pragma unroll
        for (int j = 0; j < 4; j++)
            bfr[j] = *(const short8*)(W2 + (size_t)(wn + j * 16 + l16) * 256 + k0 + quad * 8);
#pragma unroll
        for (int i = 0; i < 2; i++)
            af[i] = *(const short8*)&tS[(i * 16 + l16) * 264 + k0 + quad * 8];
#pragma unroll
        for (int i = 0; i < 2; i++)
#pragma unroll
            for (int j = 0; j < 4; j++)
                acc[i][j] = __builtin_amdgcn_mfma_f32_16x16x32_bf16(af[i], bfr[j], acc[i][j], 0, 0, 0);
    }

    float bj[4], g1j[4], b1j[4], g2j[4], b2j[4];
#pragma unroll
    for (int j = 0; j < 4; j++) {
        int col = wn + j * 16 + l16;
        bj[j] = bias[col];
        g1j[j] = g1[col]; b1j[j] = bb1[col];
        g2j[j] = g2[col]; b2j[j] = bb2[col];
    }
    // fold bias once
#pragma unroll
    for (int i = 0; i < 2; i++)
#pragma unroll
        for (int j = 0; j < 4; j++)
#pragma unroll
            for (int rg = 0; rg < 4; rg++) acc[i][j][rg] += bj[j];
#pragma unroll
    for (int i = 0; i < 2; i++)
#pragma unroll
        for (int rg = 0; rg < 4; rg++) {
            float p = 0.0f, q = 0.0f;
#pragma unroll
            for (int j = 0; j < 4; j++) {
                float v = acc[i][j][rg];
                p += v; q += v * v;
            }
            p = sum16(p);
            q = sum16(q);
            if (l16 == 0) {
                int rl = i * 16 + quad * 4 + rg;
                redS[wave][rl] = p;
                redS2[wave][rl] = q;
            }
        }
    __syncthreads();
#pragma unroll
    for (int i = 0; i < 2; i++)
#pragma unroll
        for (int rg = 0; rg < 4; rg++) {
            int rl = i * 16 + quad * 4 + rg;
            float s = redS[0][rl] + redS[1][rl] + redS[2][rl] + redS[3][rl];
            float qq = redS2[0][rl] + redS2[1][rl] + redS2[2][rl] + redS2[3][rl];
            float mean = s * (1.0f / 256.0f);
            float rstd = 1.0f / sqrtf(qq * (1.0f / 256.0f) - mean * mean + 1e-5f);
#pragma unroll
            for (int j = 0; j < 4; j++) {
                int col = wn + j * 16 + l16;
                float hu = (acc[i][j][rg] - mean) * rstd * g1j[j] + b1j[j];
                acc[i][j][rg] = hu + h_in[(size_t)(m0 + rl) * 256 + col];
            }
        }
    __syncthreads();
#pragma unroll
    for (int i = 0; i < 2; i++)
#pragma unroll
        for (int rg = 0; rg < 4; rg++) {
            float p = 0.0f, q = 0.0f;
#pragma unroll
            for (int j = 0; j < 4; j++) {
                float v = acc[i][j][rg];
                p += v; q += v * v;
            }
            p = sum16(p);
            q = sum16(q);
            if (l16 == 0) {
                int rl = i * 16 + quad * 4 + rg;
                redS[wave][rl] = p;
                redS2[wave][rl] = q;
            }
        }
    __syncthreads();
#pragma unroll
    for (int i = 0; i < 2; i++)
#pragma unroll
        for (int rg = 0; rg < 4; rg++) {
            int rl = i * 16 + quad * 4 + rg;
            float s = redS[0][rl] + redS[1][rl] + redS[2][rl] + redS[3][rl];
            float qq = redS2[0][rl] + redS2[1][rl] + redS2[2][rl] + redS2[3][rl];
            float mean = s * (1.0f / 256.0f);
            float rstd = 1.0f / sqrtf(qq * (1.0f / 256.0f) - mean * mean + 1e-5f);
            size_t orow = (size_t)(m0 + rl) * 256;
            float y0 = (acc[i][0][rg] - mean) * rstd * g2j[0] + b2j[0];
            float y1 = (acc[i][1][rg] - mean) * rstd * g2j[1] + b2j[1];
            float y2 = (acc[i][2][rg] - mean) * rstd * g2j[2] + b2j[2];
            float y3 = (acc[i][3][rg] - mean) * rstd * g2j[3] + b2j[3];
            h[orow + wn + l16]      = y0;
            h[orow + wn + 16 + l16] = y1;
            h[orow + wn + 32 + l16] = y2;
            h[orow + wn + 48 + l16] = y3;
            unsigned int pA = cvt_pk_bf16(y0, y1);
            unsigned int pB = cvt_pk_bf16(y2, y3);
            unsigned short* hb = h_bf + orow + wn + l16;
            hb[0]  = (unsigned short)pA;
            hb[16] = (unsigned short)(pA >> 16);
            hb[32] = (unsigned short)pB;
            hb[48] = (unsigned short)(pB >> 16);
        }
}

// ============ fused node GEMM + LN epilogue (attn-out path; M=32, direct-B) ============
// Grid = NTOT/32.
__global__ __launch_bounds__(256) void node_fused_kernel(
    const unsigned short* __restrict__ A, const unsigned short* __restrict__ W,
    const float* __restrict__ bias,
    const float* __restrict__ g1, const float* __restrict__ b1,
    float* __restrict__ h, unsigned short* __restrict__ h_bf)
{
    __shared__ __align__(16) unsigned short As[32 * 32];
    __shared__ float redS[4][32];
    __shared__ float redS2[4][32];
    const int tid = threadIdx.x;
    const int lane = tid & 63, wave = tid >> 6;
    const int quad = lane >> 4, l16 = lane & 15;
    const int wn = wave * 64;
    const int m0 = blockIdx.x * 32;
    f32x4 acc[2][4] = {};

    for (int k0 = 0; k0 < 256; k0 += 32) {
        {
            int r = tid >> 3, kg = (tid & 7) * 4;
            *(ushort4*)&As[r * 32 + kg] =
                *(const ushort4*)(A + (size_t)(m0 + r) * 256 + k0 + kg);
        }
        __syncthreads();
        short8 bfr[4];
#pragma unroll
        for (int j = 0; j < 4; j++)
            bfr[j] = *(const short8*)(W + (size_t)(wn + j * 16 + l16) * 256 + k0 + quad * 8);
#pragma unroll
        for (int i = 0; i < 2; i++) {
            short8 af = *(const short8*)&As[(i * 16 + l16) * 32 + quad * 8];
#pragma unroll
            for (int j = 0; j < 4; j++)
                acc[i][j] = __builtin_amdgcn_mfma_f32_16x16x32_bf16(af, bfr[j], acc[i][j], 0, 0, 0);
        }
        __syncthreads();
    }

    float bj[4], g1j[4], b1j[4];
#pragma unroll
    for (int j = 0; j < 4; j++) {
        int col = wn + j * 16 + l16;
        bj[j] = bias[col];
        g1j[j] = g1[col]; b1j[j] = b1[col];
    }

#pragma unroll
    for (int i = 0; i < 2; i++)
#pragma unroll
        for (int rg = 0; rg < 4; rg++) {
            int rl = i * 16 + quad * 4 + rg;
#pragma unroll
            for (int j = 0; j < 4; j++) {
                int col = wn + j * 16 + l16;
                acc[i][j][rg] += bj[j] + h[(size_t)(m0 + rl) * 256 + col];
            }
        }
#pragma unroll
    for (int i = 0; i < 2; i++)
#pragma unroll
        for (int rg = 0; rg < 4; rg++) {
            float p = 0.0f, q = 0.0f;
#pragma unroll
            for (int j = 0; j < 4; j++) {
                float v = acc[i][j][rg];
                p += v; q += v * v;
            }
            p = sum16(p);
            q = sum16(q);
            if (l16 == 0) {
                int rl = i * 16 + quad * 4 + rg;
                redS[wave][rl] = p;
                redS2[wave][rl] = q;
            }
        }
    __syncthreads();
#pragma unroll
    for (int i = 0; i < 2; i++)
#pragma unroll
        for (int rg = 0; rg < 4; rg++) {
            int rl = i * 16 + quad * 4 + rg;
            float s = redS[0][rl] + redS[1][rl] + redS[2][rl] + redS[3][rl];
            float qq = redS2[0][rl] + redS2[1][rl] + redS2[2][rl] + redS2[3][rl];
            float mean = s * (1.0f / 256.0f);
            float rstd = 1.0f / sqrtf(qq * (1.0f / 256.0f) - mean * mean + 1e-5f);
            size_t orow = (size_t)(m0 + rl) * 256;
            float y0 = (acc[i][0][rg] - mean) * rstd * g1j[0] + b1j[0];
            float y1 = (acc[i][1][rg] - mean) * rstd * g1j[1] + b1j[1];
            float y2 = (acc[i][2][rg] - mean) * rstd * g1j[2] + b1j[2];
            float y3 = (acc[i][3][rg] - mean) * rstd * g1j[3] + b1j[3];
            h[orow + wn + l16]      = y0;
            h[orow + wn + 16 + l16] = y1;
            h[orow + wn + 32 + l16] = y2;
            h[orow + wn + 48 + l16] = y3;
            unsigned int pA = cvt_pk_bf16(y0, y1);
            unsigned int pB = cvt_pk_bf16(y2, y3);
            unsigned short* hb = h_bf + orow + wn + l16;
            hb[0]  = (unsigned short)pA;
            hb[16] = (unsigned short)(pA >> 16);
            hb[32] = (unsigned short)pB;
            hb[48] = (unsigned short)(pB >> 16);
        }
}

// ================= fused QKV projection + MFMA attention =================
// One block per graph. Wave w handles heads {w, w+4} in 2 passes.
__global__ __launch_bounds__(256) void qkv_attn_kernel(
    const unsigned short* __restrict__ hB, const unsigned short* __restrict__ W,
    const float* __restrict__ bias, unsigned short* __restrict__ o)
{
    __shared__ __align__(16) unsigned short As[64 * 32];       // 4 KB
    __shared__ __align__(16) unsigned short scr[4][5120];      // 40 KB: q(64x40)+k(64x40) / P(64x72)
    __shared__ __align__(16) unsigned short vtS[4][32 * 72];   // 18.4 KB
    const int g = blockIdx.x;
    const int tid = threadIdx.x;
    const int lane = tid & 63, wave = tid >> 6;
    const int quad = lane >> 4, l16 = lane & 15;
    const int m0 = g * 64;
    const int rbase = lane >> 2;
    const int kk = (lane & 3) * 8;
    const float scale = 0.17677669529663687f;   // 1/sqrt(32)

#pragma unroll
    for (int s = 0; s < 2; s++) {
        const int hh = wave + s * 4;
        f32x4 acc[4][6];
#pragma unroll
        for (int i = 0; i < 4; i++)
#pragma unroll
            for (int jt = 0; jt < 6; jt++) acc[i][jt] = (f32x4){0.f, 0.f, 0.f, 0.f};

        for (int k0 = 0; k0 < 256; k0 += 32) {
            {
                int r = wave * 16 + rbase;
                async_copy16(hB + (size_t)(m0 + r) * 256 + k0 + kk, &As[wave * 512 + lane * 8]);
            }
            __syncthreads();
            short8 af[4], bfr[6];
#pragma unroll
            for (int jt = 0; jt < 6; jt++) {
                int n = (jt >> 1) * 256 + hh * 32 + (jt & 1) * 16 + l16;
                bfr[jt] = *(const short8*)(W + (size_t)n * 256 + k0 + quad * 8);
            }
#pragma unroll
            for (int i = 0; i < 4; i++)
                af[i] = *(const short8*)&As[(i * 16 + l16) * 32 + quad * 8];
#pragma unroll
            for (int i = 0; i < 4; i++)
#pragma unroll
                for (int jt = 0; jt < 6; jt++)
                    acc[i][jt] = __builtin_amdgcn_mfma_f32_16x16x32_bf16(af[i], bfr[jt], acc[i][jt], 0, 0, 0);
            __syncthreads();
        }

        // epilogue: q,k -> scr (stride 40), v -> vtS transposed (stride 72)
        unsigned short* qb = &scr[wave][0];
        unsigned short* kb = &scr[wave][2560];
#pragma unroll
        for (int seg = 0; seg < 3; seg++) {
            float bi0 = bias[seg * 256 + hh * 32 + l16];
            float bi1 = bias[seg * 256 + hh * 32 + 16 + l16];
#pragma unroll
            for (int i = 0; i < 4; i++)
#pragma unroll
                for (int rg = 0; rg < 4; rg++) {
                    int row = i * 16 + quad * 4 + rg;
                    unsigned int pk = cvt_pk_bf16(acc[i][seg * 2][rg] + bi0,
                                                  acc[i][seg * 2 + 1][rg] + bi1);
                    unsigned short lo = (unsigned short)pk;
                    unsigned short hi = (unsigned short)(pk >> 16);
                    if (seg == 0)      { qb[row * 40 + l16] = lo; qb[row * 40 + 16 + l16] = hi; }
                    else if (seg == 1) { kb[row * 40 + l16] = lo; kb[row * 40 + 16 + l16] = hi; }
                    else { vtS[wave][l16 * 72 + row] = lo; vtS[wave][(16 + l16) * 72 + row] = hi; }
                }
        }
        // load Q/K frags before P overwrites scr
        short8 aq[4], bk[4];
#pragma unroll
        for (int i = 0; i < 4; i++)
            aq[i] = *(const short8*)&qb[(i * 16 + l16) * 40 + quad * 8];
#pragma unroll
        for (int j = 0; j < 4; j++)
            bk[j] = *(const short8*)&kb[(j * 16 + l16) * 40 + quad * 8];
        __asm__ __volatile__("s_waitcnt lgkmcnt(0)" ::: "memory");

        // S = Q @ K^T
        f32x4 sc[4][4];
#pragma unroll
        for (int i = 0; i < 4; i++)
#pragma unroll
            for (int j = 0; j < 4; j++) sc[i][j] = (f32x4){0.f, 0.f, 0.f, 0.f};
#pragma unroll
        for (int i = 0; i < 4; i++)
#pragma unroll
            for (int j = 0; j < 4; j++)
                sc[i][j] = __builtin_amdgcn_mfma_f32_16x16x32_bf16(aq[i], bk[j], sc[i][j], 0, 0, 0);
        // softmax -> P in scr (stride 72)
        unsigned short* pb = &scr[wave][0];
#pragma unroll
        for (int i = 0; i < 4; i++)
#pragma unroll
            for (int rg = 0; rg < 4; rg++) {
                float v[4];
                float mx = -1e30f;
#pragma unroll
                for (int j = 0; j < 4; j++) {
                    v[j] = sc[i][j][rg] * scale;
                    mx = fmaxf(mx, v[j]);
                }
                mx = max16(mx);
                float sum = 0.0f;
#pragma unroll
                for (int j = 0; j < 4; j++) {
                    v[j] = exp_f(v[j] - mx);
                    sum += v[j];
                }
                sum = sum16(sum);
                float inv = __builtin_amdgcn_rcpf(sum);
                int row = i * 16 + quad * 4 + rg;
                unsigned int pA = cvt_pk_bf16(v[0] * inv, v[1] * inv);
                unsigned int pB = cvt_pk_bf16(v[2] * inv, v[3] * inv);
                unsigned short* pr = &pb[row * 72 + l16];
                pr[0]  = (unsigned short)pA;
                pr[16] = (unsigned short)(pA >> 16);
                pr[32] = (unsigned short)pB;
                pr[48] = (unsigned short)(pB >> 16);
            }
        // O = P @ V
        f32x4 oc[4][2];
#pragma unroll
        for (int i = 0; i < 4; i++)
#pragma unroll
            for (int j = 0; j < 2; j++) oc[i][j] = (f32x4){0.f, 0.f, 0.f, 0.f};
#pragma unroll
        for (int k0 = 0; k0 < 64; k0 += 32) {
            short8 ap[4], bv[2];
#pragma unroll
            for (int i = 0; i < 4; i++)
                ap[i] = *(const short8*)&pb[(i * 16 + l16) * 72 + k0 + quad * 8];
#pragma unroll
            for (int j = 0; j < 2; j++)
                bv[j] = *(const short8*)&vtS[wave][(j * 16 + l16) * 72 + k0 + quad * 8];
#pragma unroll
            for (int i = 0; i < 4; i++)
#pragma unroll
                for (int j = 0; j < 2; j++)
                    oc[i][j] = __builtin_amdgcn_mfma_f32_16x16x32_bf16(ap[i], bv[j], oc[i][j], 0, 0, 0);
        }
#pragma unroll
        for (int i = 0; i < 4; i++)
#pragma unroll
            for (int rg = 0; rg < 4; rg++) {
                int row = i * 16 + quad * 4 + rg;
                unsigned short* ob = o + (size_t)(m0 + row) * 256 + hh * 32;
                unsigned int pk = cvt_pk_bf16(oc[i][0][rg], oc[i][1][rg]);
                ob[l16]      = (unsigned short)pk;
                ob[16 + l16] = (unsigned short)(pk >> 16);
            }
    }
}

extern "C" void kernel_launch(void* const* d_in, const int* in_sizes, int n_in,
                              void* d_out, int out_size, void* d_ws, size_t ws_size,
                              hipStream_t stream)
{
    const float* x    = (const float*)d_in[0];
    const float* pos  = (const float*)d_in[1];
    const int*   ei   = (const int*)d_in[2];
    const float* pe_w1 = (const float*)d_in[5];
    const float* pe_b1 = (const float*)d_in[6];
    const float* pe_w2 = (const float*)d_in[7];
    const float* pe_b2 = (const float*)d_in[8];
    const float* pe_lg = (const float*)d_in[9];
    const float* pe_lb = (const float*)d_in[10];
    const float* ph_w1 = (const float*)d_in[11];
    const float* ph_b1 = (const float*)d_in[12];
    const float* ph_w2 = (const float*)d_in[13];
    const float* ph_b2 = (const float*)d_in[14];
    const float* ph_lg = (const float*)d_in[15];
    const float* ph_lb = (const float*)d_in[16];
    const float* px_w1 = (const float*)d_in[17];
    const float* px_b1 = (const float*)d_in[18];
    const float* px_w2 = (const float*)d_in[19];
    const float* px_b2 = (const float*)d_in[20];
    const float* ain_w = (const float*)d_in[21];
    const float* ain_b = (const float*)d_in[22];
    const float* aout_w = (const float*)d_in[23];
    const float* aout_b = (const float*)d_in[24];
    const float* lnh_g = (const float*)d_in[25];
    const float* lnh_b = (const float*)d_in[26];
    const float* lna_g = (const float*)d_in[27];
    const float* lna_b = (const float*)d_in[28];
    const float* ff_w1 = (const float*)d_in[29];
    const float* ff_b1 = (const float*)d_in[30];
    const float* ff_w2 = (const float*)d_in[31];
    const float* ff_b2 = (const float*)d_in[32];
    const float* ps    = (const float*)d_in[33];

    char* p = (char*)d_ws;
    auto alloc = [&](size_t bytes) { char* r = p; p += (bytes + 63) & ~(size_t)63; return r; };
    float* h      = (float*)alloc((size_t)NTOTC * HC * 4);
    unsigned short* h_bf  = (unsigned short*)alloc((size_t)NTOTC * HC * 2);
    unsigned short* xcat_bf = (unsigned short*)alloc((size_t)NTOTC * 512 * 2);
    float* cur    = (float*)alloc((size_t)NTOTC * 3 * 4);
    float* posupd = (float*)alloc((size_t)NTOTC * 3 * 4);
    float* hmsg   = (float*)alloc((size_t)NTOTC * HC * 4);
    unsigned short* o_bf   = (unsigned short*)alloc((size_t)NTOTC * HC * 2);
    unsigned short* ff1_bf = (unsigned short*)alloc((size_t)NTOTC * 4 * HC * 2);
    int* cnt  = (int*)alloc(16384 * 4);
    int* ptrw = (int*)alloc(16384 * 4);
    int* rowP = (int*)alloc((size_t)NEDGEC * 4);
    int* colP = (int*)alloc((size_t)NEDGEC * 4);
    float* zbias = (float*)alloc(512 * 4);
    unsigned short* w_pe1s = (unsigned short*)alloc((size_t)LC * 512 * 256 * 2);
    float*          w_last = (float*)alloc((size_t)LC * 256 * 4);
    unsigned short* w_pe2  = (unsigned short*)alloc((size_t)LC * 256 * 256 * 2);
    unsigned short* w_ph1  = (unsigned short*)alloc((size_t)LC * 256 * 256 * 2);
    unsigned short* w_ph2  = (unsigned short*)alloc((size_t)LC * 256 * 256 * 2);
    unsigned short* w_px1  = (unsigned short*)alloc((size_t)LC * 256 * 256 * 2);
    unsigned short* w_ain  = (unsigned short*)alloc((size_t)LC * 768 * 256 * 2);
    unsigned short* w_aout = (unsigned short*)alloc((size_t)LC * 256 * 256 * 2);
    unsigned short* w_ff1  = (unsigned short*)alloc((size_t)LC * 1024 * 256 * 2);
    unsigned short* w_ff2  = (unsigned short*)alloc((size_t)LC * 256 * 1024 * 2);

    // ---- counting sort of edges by col ----
    hipMemsetAsync(cnt, 0, 16384 * 4, stream);
    hipMemsetAsync(zbias, 0, 512 * 4, stream);
    hist_kernel<<<NEDGEC / 256, 256, 0, stream>>>(ei + NEDGEC, cnt);
    scan16k_kernel<<<1, 256, 0, stream>>>(cnt, ptrw);
    permute_kernel<<<NEDGEC / 256, 256, 0, stream>>>(ei, ei + NEDGEC, ptrw, rowP, colP);

    // ---- convert weights to bf16 ----
    conv_pe1_kernel<<<(LC * 256 * 513 + 255) / 256, 256, 0, stream>>>(pe_w1, w_pe1s, w_last);
    conv_bf16_kernel<<<1536, 256, 0, stream>>>(pe_w2, w_pe2, LC * 256 * 256);
    conv_bf16_kernel<<<1536, 256, 0, stream>>>(ph_w1, w_ph1, LC * 256 * 256);
    conv_bf16_kernel<<<1536, 256, 0, stream>>>(ph_w2, w_ph2, LC * 256 * 256);
    conv_bf16_kernel<<<1536, 256, 0, stream>>>(px_w1, w_px1, LC * 256 * 256);
    conv_bf16_kernel<<<4608, 256, 0, stream>>>(ain_w, w_ain, LC * 768 * 256);
    conv_bf16_kernel<<<1536, 256, 0, stream>>>(aout_w, w_aout, LC * 256 * 256);
    conv_bf16_kernel<<<6144, 256, 0, stream>>>(ff_w1, w_ff1, LC * 1024 * 256);
    conv_bf16_kernel<<<6144, 256, 0, stream>>>(ff_w2, w_ff2, LC * 256 * 1024);

    hipMemcpyAsync(h, x, (size_t)NTOTC * HC * 4, hipMemcpyDeviceToDevice, stream);
    hipMemcpyAsync(cur, pos, (size_t)NTOTC * 3 * 4, hipMemcpyDeviceToDevice, stream);
    conv_bf16_kernel<<<4096, 256, 0, stream>>>(x, h_bf, NTOTC * HC);
    // zero accumulators once; per-layer re-zero is fused into phi_h
    hipMemsetAsync(hmsg, 0, (size_t)NTOTC * HC * 4, stream);
    hipMemsetAsync(posupd, 0, (size_t)NTOTC * 3 * 4, stream);

    for (int l = 0; l < LC; l++) {
        // xcat = h @ [W1a;W1b]^T   (MT=64: 1024 blocks, 4/CU)
        mgemm_kernel<64, 0, false, false, true><<<dim3(NTOTC / 64, 4), 256, 0, stream>>>(
            h_bf, w_pe1s + (size_t)l * 512 * 256, zbias,
            nullptr, nullptr, xcat_bf, NTOTC, 512, HC);

        fused_edge_kernel<<<NEDGEC / 64, 256, 0, stream>>>(
            xcat_bf, cur, rowP, colP,
            w_last + (size_t)l * 256, pe_b1 + (size_t)l * HC,
            w_pe2 + (size_t)l * 256 * 256, pe_b2 + (size_t)l * HC,
            pe_lg + (size_t)l * HC, pe_lb + (size_t)l * HC,
            w_px1 + (size_t)l * 256 * 256, px_b1 + (size_t)l * HC,
            px_w2 + (size_t)l * HC, px_b2 + l,
            hmsg, posupd);

        // phi_h fully fused (+ cur update + posupd/hmsg re-zero); M=32 grid
        phi_h_fused_kernel<<<NTOTC / 32, 256, 0, stream>>>(
            h, hmsg,
            w_ph1 + (size_t)l * 256 * 256, ph_b1 + (size_t)l * HC,
            w_ph2 + (size_t)l * 256 * 256, ph_b2 + (size_t)l * HC,
            ph_lg + (size_t)l * HC, ph_lb + (size_t)l * HC,
            lnh_g + (size_t)l * HC, lnh_b + (size_t)l * HC, h, h_bf,
            cur, posupd, ps, l);

        // fused qkv projection + attention
        qkv_attn_kernel<<<NTOTC / 64, 256, 0, stream>>>(
            h_bf, w_ain + (size_t)l * 768 * 256, ain_b + (size_t)l * 3 * HC, o_bf);
        node_fused_kernel<<<NTOTC / 32, 256, 0, stream>>>(
            o_bf, w_aout + (size_t)l * 256 * 256, aout_b + (size_t)l * HC,
            lna_g + (size_t)l * HC, lna_b + (size_t)l * HC, h, h_bf);

        // feed-forward with residual
        mgemm_kernel<128, 2, false, false, true><<<dim3(NTOTC / 128, 8), 256, 0, stream>>>(
            h_bf, w_ff1 + (size_t)l * 1024 * 256, ff_b1 + (size_t)l * 4 * HC,
            nullptr, nullptr, ff1_bf, NTOTC, 4 * HC, HC);
        mgemm_kernel<64, 0, true, true, true><<<dim3(NTOTC / 64, 2), 256, 0, stream>>>(
            ff1_bf, w_ff2 + (size_t)l * 256 * 1024, ff_b2 + (size_t)l * HC,
            h, h, h_bf, NTOTC, HC, 4 * HC);
    }

    hipMemcpyAsync(d_out, h, (size_t)NTOTC * HC * 4, hipMemcpyDeviceToDevice, stream);
    hipMemcpyAsync((float*)d_out + (size_t)NTOTC * HC, cur, (size_t)NTOTC * 3 * 4,
                   hipMemcpyDeviceToDevice, stream);
}